// Round 7
// baseline (671.054 us; speedup 1.0000x reference)
//
#include <hip/hip_runtime.h>
#include <hip/hip_bf16.h>
#include <math.h>

#define T_LEN   320000
#define NB      16
#define NROWS   32          // 16 batch * 2 ch
#define NFRAMES 625
#define NCOMP   67
#define NCH     150
#define HOPSZ   512

typedef __attribute__((ext_vector_type(8))) short short8v;
typedef __attribute__((ext_vector_type(4))) float f32x4;

// per-window constants
__constant__ int cW_N[6]  = {2048,1024,512,256,128,64};
__constant__ int cW_K0[6] = {2,3,8,10,11,9};
__constant__ int cW_CB[7] = {0,4,17,29,40,46,67};
__constant__ int cW_CO[7] = {0,8192,21504,27648,30464,31232,32576};
// fused-coefficient geometry (per window)
__constant__ int dNEp[6]  = {3072,2048,1536,1280,1152,1152};
__constant__ int dNEr[6]  = {3072,2048,1536,1280,1152,1088};
__constant__ int dBTb[7]  = {0,147456,245760,319488,380928,436224,491520}; // [w][col=48][k=NEp] ushort
// init_fused chunk mapping
__constant__ int dCPB[6]  = {12,8,6,5,5,5};
__constant__ int dCKB[7]  = {0,48,152,224,279,309,414};
// edge task list
__constant__ int eW[8] = {0,0,0,1,2,3,4,5};
__constant__ int eF[8] = {0,1,624,0,0,0,0,0};

// ================= setup: tables + fused bf16 B + edge FIR, branch by blockIdx =================
// blocks [0,167): init_tables ; [167,581): init_fused ; [581,965): edge_y
__global__ __launch_bounds__(256) void setup_k(const float* __restrict__ h,
                                               const float* __restrict__ x,
                                               float2* __restrict__ coeff,
                                               float* __restrict__ Wmat,
                                               float* __restrict__ gauss,
                                               unsigned short* __restrict__ Bhi,
                                               unsigned short* __restrict__ Blo,
                                               float* __restrict__ ye) {
  __shared__ float sm[3585];
  const int bid = blockIdx.x, tid = threadIdx.x;
  if (bid < 167) {
    int gid = bid * 256 + tid;
    if (gid < 32576) {
      int w = 0;
      while (gid >= cW_CO[w + 1]) ++w;
      int local = gid - cW_CO[w];
      int N = cW_N[w];
      int jloc = local / N;
      int n = local - jloc * N;
      int k = cW_K0[w] + jloc;
      float win = 0.5f - 0.5f * cospif(2.0f * (float)n / (float)(N - 1));
      int r = (int)(((long long)k * (long long)n) % (long long)N);
      float ang = 2.0f * (float)r / (float)N;
      float scale = sqrtf(2.0f) / (0.5f * (float)(N - 1));
      float wc = win * scale;
      coeff[gid] = make_float2(wc * cospif(ang), wc * sinpif(ang));
    } else if (gid < 32576 + NCOMP * NCH) {
      int t = gid - 32576;
      int j = t / NCH, c = t - j * NCH;
      float erb = 1.75f + 0.25f * (float)c;
      float fc = (exp10f(erb * (1.0f / 21.366f)) - 1.0f) * (1.0f / 0.004368f);
      float erbw = 24.673f * (0.004368f * fc + 1.0f);
      float p = 4.0f * fc / erbw;
      int w = 0;
      while (j >= cW_CB[w + 1]) ++w;
      float freq = (float)(cW_K0[w] + (j - cW_CB[w])) * (32000.0f / (float)cW_N[w]);
      float g = fabsf(freq / fc - 1.0f);
      float pg = p * g;
      Wmat[j * NCH + c] = (1.0f + pg) * expf(-pg);
    } else if (gid == 32576 + NCOMP * NCH) {
      float tmp[17]; float s = 0.0f;
      for (int k = 0; k < 17; ++k) {
        float g = ((float)k - 8.0f) * 0.25f;
        tmp[k] = expf(-g * g / (2.0f * 0.08f * 0.08f));
        s += tmp[k];
      }
      for (int k = 0; k < 17; ++k) gauss[k] = tmp[k] / s;
    }
  } else if (bid < 581) {
    float* cre_l = sm;          // 1280
    float* cim_l = sm + 1280;   // 1280
    float* hs    = sm + 2560;   // 1025
    const int b2 = bid - 167;
    int w = 0;
    while (b2 >= dCKB[w + 1]) ++w;
    const int local = b2 - dCKB[w];
    const int jloc = local / dCPB[w];
    const int chunk = local - jloc * dCPB[w];
    const int N = cW_N[w];
    const int k = cW_K0[w] + jloc;
    const int NEp = dNEp[w], NEr = dNEr[w];
    const int v0 = chunk * 256;
    const int nlo_blk = max(0, v0 - 1024);
    const int nhi_blk = min(N - 1, v0 + 255);
    const int cnt_n = nhi_blk - nlo_blk + 1;
    const float scale = sqrtf(2.0f) / (0.5f * (float)(N - 1));
    for (int i = tid; i < 1025; i += 256) hs[i] = h[i];
    for (int i = tid; i < cnt_n; i += 256) {
      int n = nlo_blk + i;
      float win = 0.5f - 0.5f * cospif(2.0f * (float)n / (float)(N - 1));
      int r = (int)(((long long)k * (long long)n) % (long long)N);
      float ang = 2.0f * (float)r / (float)N;
      float wc = win * scale;
      cre_l[i] = wc * cospif(ang);
      cim_l[i] = wc * sinpif(ang);
    }
    __syncthreads();
    const int v = v0 + tid;
    if (v >= NEp) return;
    float re = 0.0f, im = 0.0f;
    if (v < NEr) {
      for (int n = nlo_blk; n <= nhi_blk; ++n) {
        int hidx = n + 1024 - v;
        if ((unsigned)hidx <= 1024u) {
          float hv = hs[hidx];
          re = fmaf(cre_l[n - nlo_blk], hv, re);
          im = fmaf(cim_l[n - nlo_blk], hv, im);
        }
      }
    }
    size_t o0 = (size_t)dBTb[w] + (size_t)(2 * jloc) * NEp + v;
    size_t o1 = o0 + NEp;
    unsigned ur = __float_as_uint(re);
    Bhi[o0] = (unsigned short)(ur >> 16);
    Blo[o0] = (unsigned short)(__float_as_uint(re - __uint_as_float(ur & 0xFFFF0000u)) >> 16);
    unsigned ui = __float_as_uint(im);
    Bhi[o1] = (unsigned short)(ui >> 16);
    Blo[o1] = (unsigned short)(__float_as_uint(im - __uint_as_float(ui & 0xFFFF0000u)) >> 16);
  } else {
    float* xl = sm;             // 1280
    float* hs = sm + 1280;      // 1025
    const int b2 = bid - 581;
    const int chunk = b2 % 12, row = b2 / 12;
    const size_t rowoff = (size_t)row * T_LEN;
    const int i0 = chunk * 256;
    const int pos0 = (i0 < 1536) ? i0 : 318464 + (i0 - 1536);
    for (int i = tid; i < 1025; i += 256) hs[i] = h[i];
    for (int i = tid; i < 1280; i += 256) {
      int g = pos0 - 512 + i;
      xl[i] = ((unsigned)g < (unsigned)T_LEN) ? x[rowoff + g] : 0.0f;
    }
    __syncthreads();
    // 4-way ILP on the serial FMA chain
    float a0 = 0.0f, a1 = 0.0f, a2 = 0.0f, a3 = 0.0f;
    const int d = tid + 1024;
    for (int m = 0; m < 1024; m += 4) {
      a0 = fmaf(hs[m],     xl[d - m],     a0);
      a1 = fmaf(hs[m + 1], xl[d - m - 1], a1);
      a2 = fmaf(hs[m + 2], xl[d - m - 2], a2);
      a3 = fmaf(hs[m + 3], xl[d - m - 3], a3);
    }
    float acc = ((a0 + a1) + (a2 + a3)) + hs[1024] * xl[d - 1024];
    ye[(size_t)row * 3072 + i0 + tid] = acc;
  }
}

// ================= MFMA fused FIR+DFT (+edge DFT blocks) =================
#define TILE_X 18944   // 31*512 + 3072
#define SWZ4(i) ((i) ^ ((((i) >> 9) & 15) << 3))

template<int W, int CT, int M0, int NM>
__device__ __forceinline__ void gemm_task(const unsigned short* sxh, const unsigned short* sxl,
                                          const unsigned short* __restrict__ Bhi,
                                          const unsigned short* __restrict__ Blo,
                                          float* __restrict__ Ibuf, int row, int f0, int lane) {
  constexpr int kNEp[6] = {3072,2048,1536,1280,1152,1152};
  constexpr int kStb[6] = {0,512,768,896,960,992};    // 1536 - (N+1024)/2
  constexpr int kNb[6]  = {4,13,12,11,6,21};
  constexpr int kJb0[6] = {0,4,17,29,40,46};
  constexpr int kBtb[6] = {0,147456,245760,319488,380928,436224};
  constexpr int NEp = kNEp[W], stb = kStb[W], nb = kNb[W], jb0 = kJb0[W];
  const int fidx = lane & 15, kg = lane >> 4;
  const unsigned short* Bh = Bhi + kBtb[W] + (size_t)((CT * 16 + fidx) * NEp + kg * 8);
  const unsigned short* Bl = Blo + kBtb[W] + (size_t)((CT * 16 + fidx) * NEp + kg * 8);
  const int ibase = fidx * 512 + stb + kg * 8;
  f32x4 acc[NM];
#pragma unroll
  for (int m = 0; m < NM; ++m) acc[m] = (f32x4){0.f, 0.f, 0.f, 0.f};
#pragma unroll 4
  for (int kk = 0; kk < NEp; kk += 32) {
    short8v bh = *(const short8v*)(Bh + kk);
    short8v bl = *(const short8v*)(Bl + kk);
#pragma unroll
    for (int m = 0; m < NM; ++m) {
      const int idx = SWZ4(ibase + (M0 + m) * 8192 + kk);
      short8v ah = *(const short8v*)(sxh + idx);
      short8v al = *(const short8v*)(sxl + idx);
      acc[m] = __builtin_amdgcn_mfma_f32_16x16x32_bf16(ah, bh, acc[m], 0, 0, 0);
      acc[m] = __builtin_amdgcn_mfma_f32_16x16x32_bf16(ah, bl, acc[m], 0, 0, 0);
      acc[m] = __builtin_amdgcn_mfma_f32_16x16x32_bf16(al, bh, acc[m], 0, 0, 0);
    }
  }
  const int col = CT * 16 + fidx;
#pragma unroll
  for (int m = 0; m < NM; ++m) {
#pragma unroll
    for (int r = 0; r < 4; ++r) {
      float v = acc[m][r];
      float sq = v * v;
      sq += __shfl_xor(sq, 1);
      int f = f0 + (M0 + m) * 16 + kg * 4 + r;
      if (!(col & 1)) {
        int j = col >> 1;
        bool edge = (f == 0) || (W == 0 && (f == 1 || f == 624));
        if (j < nb && f < NFRAMES && !edge)
          Ibuf[((size_t)row * NFRAMES + f) * NCOMP + jb0 + j] = sq;
      }
    }
  }
}

// blocks [0,640): MFMA gemm (fblk = b%20, row = b/20) ; [640,672): edge DFT (row = b-640)
__global__ __launch_bounds__(512) void sparse2(const float* __restrict__ x,
                                               const unsigned short* __restrict__ Bhi,
                                               const unsigned short* __restrict__ Blo,
                                               const float2* __restrict__ coeff,
                                               const float* __restrict__ ye,
                                               float* __restrict__ Ibuf) {
  __shared__ __align__(16) unsigned short sxh[TILE_X];
  __shared__ __align__(16) unsigned short sxl[TILE_X];
  const int b = blockIdx.x, tid = threadIdx.x;
  if (b < 640) {
    const int fblk = b % 20, row = b / 20;
    const int f0 = fblk * 32;
    const float* xr = x + (size_t)row * T_LEN;
    const int lo = f0 * HOPSZ - 1536;
    for (int i = 4 * tid; i < TILE_X; i += 2048) {
      const int g = lo + i;
      float v[4];
      if (g >= 0 && g + 4 <= T_LEN) {
        float4 p = *(const float4*)(xr + g);
        v[0] = p.x; v[1] = p.y; v[2] = p.z; v[3] = p.w;
      } else {
#pragma unroll
        for (int q = 0; q < 4; ++q) {
          int gg = g + q;
          v[q] = ((unsigned)gg < (unsigned)T_LEN) ? xr[gg] : 0.0f;
        }
      }
      unsigned short h4[4], l4[4];
#pragma unroll
      for (int q = 0; q < 4; ++q) {
        unsigned u = __float_as_uint(v[q]);
        h4[q] = (unsigned short)(u >> 16);
        float r = v[q] - __uint_as_float(u & 0xFFFF0000u);
        l4[q] = (unsigned short)(__float_as_uint(r) >> 16);
      }
      const int is = SWZ4(i);
      *(ushort4*)(sxh + is) = make_ushort4(h4[0], h4[1], h4[2], h4[3]);
      *(ushort4*)(sxl + is) = make_ushort4(l4[0], l4[1], l4[2], l4[3]);
    }
    __syncthreads();
    const int wv = tid >> 6, lane = tid & 63;
    // 11 column-tiles over 8 waves; every task keeps B-reuse across its M-tiles.
    switch (wv) {
      case 0: gemm_task<1,0,0,2>(sxh,sxl,Bhi,Blo,Ibuf,row,f0,lane); break;
      case 1: gemm_task<1,1,0,2>(sxh,sxl,Bhi,Blo,Ibuf,row,f0,lane); break;
      case 2: gemm_task<2,0,0,2>(sxh,sxl,Bhi,Blo,Ibuf,row,f0,lane);
              gemm_task<4,0,0,2>(sxh,sxl,Bhi,Blo,Ibuf,row,f0,lane); break;
      case 3: gemm_task<2,1,0,2>(sxh,sxl,Bhi,Blo,Ibuf,row,f0,lane);
              gemm_task<5,0,0,2>(sxh,sxl,Bhi,Blo,Ibuf,row,f0,lane); break;
      case 4: gemm_task<0,0,0,1>(sxh,sxl,Bhi,Blo,Ibuf,row,f0,lane);
              gemm_task<5,1,0,2>(sxh,sxl,Bhi,Blo,Ibuf,row,f0,lane); break;
      case 5: gemm_task<0,0,1,1>(sxh,sxl,Bhi,Blo,Ibuf,row,f0,lane);
              gemm_task<5,2,0,2>(sxh,sxl,Bhi,Blo,Ibuf,row,f0,lane); break;
      case 6: gemm_task<3,0,0,2>(sxh,sxl,Bhi,Blo,Ibuf,row,f0,lane); break;
      default: gemm_task<3,1,0,2>(sxh,sxl,Bhi,Blo,Ibuf,row,f0,lane); break;
    }
  } else {
    const int row = b - 640;
    float* yl = (float*)sxh;   // 12 KB alias
    for (int i = tid; i < 3072; i += 512) yl[i] = ye[(size_t)row * 3072 + i];
    __syncthreads();
    const int wv = tid >> 6, lane = tid & 63;
    const int w = eW[wv], f = eF[wv];
    const int N = cW_N[w];
    const int nb = cW_CB[w + 1] - cW_CB[w];
    for (int jl = 0; jl < nb; ++jl) {
      const float2* cf = coeff + cW_CO[w] + (size_t)jl * N;
      float re = 0.0f, im = 0.0f;
      for (int n = lane; n < N; n += 64) {
        int pos = f * HOPSZ - (N >> 1) + n;
        if ((unsigned)pos < (unsigned)T_LEN) {
          int yi = (pos < 1536) ? pos : (pos - 318464 + 1536);
          float yv = yl[yi];
          float2 cs = cf[n];
          re = fmaf(yv, cs.x, re);
          im = fmaf(yv, cs.y, im);
        }
      }
#pragma unroll
      for (int off = 32; off > 0; off >>= 1) {
        re += __shfl_xor(re, off);
        im += __shfl_xor(im, off);
      }
      if (lane == 0)
        Ibuf[((size_t)row * NFRAMES + f) * NCOMP + (cW_CB[w] + jl)] = re * re + im * im;
    }
  }
}

// ================= E = I@W -> dB -> LUT -> n_inst, 16 frames per block =================
__global__ __launch_bounds__(256) void espec(const float* __restrict__ Ibuf,
                                             const float* __restrict__ Wmat,
                                             const float* __restrict__ lut,
                                             float* __restrict__ ninst) {
  __shared__ float Is[16][68];
  __shared__ float luts[88];
  const int row = blockIdx.y;
  const int fb = blockIdx.x * 16;
  const int tid = threadIdx.x;
  if (tid < 88) luts[tid] = lut[tid];
  for (int u = tid; u < 16 * NCOMP; u += 256) {
    int fi = u / NCOMP, j = u - fi * NCOMP;
    int f = fb + fi;
    Is[fi][j] = (f < NFRAMES) ? Ibuf[((size_t)row * NFRAMES + f) * NCOMP + j] : 0.0f;
  }
  __syncthreads();
  for (int u = tid; u < 16 * NCH; u += 256) {
    int fi = u / NCH, c = u - fi * NCH;
    int f = fb + fi;
    if (f >= NFRAMES) continue;
    float e = 0.0f;
#pragma unroll 4
    for (int j = 0; j < NCOMP; ++j) e = fmaf(Is[fi][j], Wmat[j * NCH + c], e);
    float edb = 10.0f * log10f(e * 2.5e9f + 1e-12f);   // 1/I0 = 2.5e9
    float xv = fminf(fmaxf(edb, 0.0f), 110.0f);
    float u2 = xv * (87.0f / 110.0f);
    int i0 = (int)u2; if (i0 > 86) i0 = 86;
    float fr = u2 - (float)i0;
    float nv = fmaf(luts[i0 + 1] - luts[i0], fr, luts[i0]);
    ninst[((size_t)row * NFRAMES + f) * NCH + c] = nv;
  }
}

// ================= short-term AGC over frames (8-ahead ring prefetch, no shifts) =================
__global__ void agc1(const float* __restrict__ ninst, float* __restrict__ stl) {
  int idx = blockIdx.x * 64 + threadIdx.x;
  if (idx >= NROWS * NCH) return;
  int row = idx / NCH, c = idx - row * NCH;
  const float* src = ninst + (size_t)row * NFRAMES * NCH + c;
  float* dst = stl + (size_t)row * NFRAMES * NCH + c;
  float buf[8];
#pragma unroll
  for (int i = 0; i < 8; ++i) buf[i] = src[(size_t)i * NCH];
  float s = 0.0f;
  for (int fb = 0; fb < NFRAMES; fb += 8) {
#pragma unroll
    for (int j = 0; j < 8; ++j) {
      int f = fb + j;
      if (f >= NFRAMES) break;
      float xv = buf[j];
      int nf = f + 8;
      buf[j] = (nf < NFRAMES) ? src[(size_t)nf * NCH] : 0.0f;
      float a = (xv > s) ? 0.045f : 0.033f;
      s = a * xv + (1.0f - a) * s;
      dst[(size_t)f * NCH] = s;
    }
  }
}

// ================= ERB smoothing + binaural inhibition + channel sum, 8 frames/block =================
__global__ __launch_bounds__(256) void combine(const float* __restrict__ stl,
                                               const float* __restrict__ gauss,
                                               float* __restrict__ outL,
                                               float* __restrict__ outR) {
  __shared__ float sl[8][168], sr[8][168], gsh[17];
  const int b = blockIdx.y, fb = blockIdx.x * 8;
  const int tid = threadIdx.x;
  if (tid < 17) gsh[tid] = gauss[tid];
  for (int u = tid; u < 8 * 168; u += 256) {
    int fi = u / 168, c = u - fi * 168;
    sl[fi][c] = 0.0f; sr[fi][c] = 0.0f;
  }
  __syncthreads();
  for (int u = tid; u < 8 * 300; u += 256) {
    int fi = u / 300, r = u - fi * 300;
    int f = fb + fi;
    if (f < NFRAMES) {
      int ch = (r < NCH) ? 0 : 1;
      int c = (r < NCH) ? r : r - NCH;
      float v = stl[((size_t)(b * 2 + ch) * NFRAMES + f) * NCH + c];
      if (ch == 0) sl[fi][8 + c] = v; else sr[fi][8 + c] = v;
    }
  }
  __syncthreads();
  const int wv = tid >> 6, lane = tid & 63;
#pragma unroll
  for (int fi2 = 0; fi2 < 2; ++fi2) {
    const int fi = wv * 2 + fi2;
    const int f = fb + fi;
    float pvl = 0.0f, pvr = 0.0f;
#pragma unroll
    for (int s = 0; s < 3; ++s) {
      int c = lane + 64 * s;
      if (c < NCH) {
        float smL = 0.0f, smR = 0.0f;
#pragma unroll
        for (int t = 0; t < 17; ++t) {
          smL = fmaf(gsh[t], sl[fi][c + t], smL);
          smR = fmaf(gsh[t], sr[fi][c + t], smR);
        }
        pvl += smL / coshf(1.5978f * smR);
        pvr += smR / coshf(1.5978f * smL);
      }
    }
#pragma unroll
    for (int off = 32; off > 0; off >>= 1) {
      pvl += __shfl_xor(pvl, off);
      pvr += __shfl_xor(pvr, off);
    }
    if (lane == 0 && f < NFRAMES) {
      outL[b * NFRAMES + f] = pvl * 0.25f;
      outR[b * NFRAMES + f] = pvr * 0.25f;
    }
  }
}

// ================= long-term AGC + outputs (8-ahead ring prefetch) =================
__global__ void final_k(const float* __restrict__ sLst, const float* __restrict__ sRst,
                        float* __restrict__ out) {
  int b = threadIdx.x;
  if (b >= NB) return;
  float ll = 0.0f, lr = 0.0f, mx = -3.4e38f;
  float* sOut = out;
  float* lOut = out + NB * NFRAMES;
  float* mOut = out + 2 * NB * NFRAMES;
  float bufa[8], bufc[8];
#pragma unroll
  for (int i = 0; i < 8; ++i) { bufa[i] = sLst[b * NFRAMES + i]; bufc[i] = sRst[b * NFRAMES + i]; }
  for (int fb = 0; fb < NFRAMES; fb += 8) {
#pragma unroll
    for (int j = 0; j < 8; ++j) {
      int f = fb + j;
      if (f >= NFRAMES) break;
      float a = bufa[j], c = bufc[j];
      int nf = f + 8;
      bufa[j] = (nf < NFRAMES) ? sLst[b * NFRAMES + nf] : 0.0f;
      bufc[j] = (nf < NFRAMES) ? sRst[b * NFRAMES + nf] : 0.0f;
      sOut[b * NFRAMES + f] = a + c;
      float aa = (a > ll) ? 0.01f : 0.00133f;
      ll = aa * a + (1.0f - aa) * ll;
      float ab = (c > lr) ? 0.01f : 0.00133f;
      lr = ab * c + (1.0f - ab) * lr;
      float lv = ll + lr;
      lOut[b * NFRAMES + f] = lv;
      mx = fmaxf(mx, lv);
    }
  }
  mOut[b] = mx;
}

extern "C" void kernel_launch(void* const* d_in, const int* in_sizes, int n_in,
                              void* d_out, int out_size, void* d_ws, size_t ws_size,
                              hipStream_t stream) {
  const float* audio = (const float*)d_in[0];
  const float* ear   = (const float*)d_in[1];
  const float* lut   = (const float*)d_in[2];
  char* ws = (char*)d_ws;

  unsigned short* BhiT   = (unsigned short*)(ws);            //   983,040 B
  unsigned short* BloT   = (unsigned short*)(ws + 983040);   //   983,040 B
  float2*         coeffO = (float2*)(ws + 1966080);          //   260,608 B
  float*          Wmat   = (float*)(ws + 2226688);           //    40,200 B
  float*          gauss  = (float*)(ws + 2266888);           //        68 B
  float*          yedge  = (float*)(ws + 2266960);           //   393,216 B
  float*          Ibuf   = (float*)(ws + 2660176);           // 5,360,000 B
  float*          ninst  = (float*)(ws + 8020176);           // 12,000,000 B
  float*          stl    = (float*)(ws + 20020176);          // 12,000,000 B
  float*          stlL   = (float*)(ws + 32020176);          //    40,000 B
  float*          stlR   = (float*)(ws + 32060176);          //    40,000 B

  hipLaunchKernelGGL(setup_k, dim3(965), dim3(256), 0, stream,
                     ear, audio, coeffO, Wmat, gauss, BhiT, BloT, yedge);
  hipLaunchKernelGGL(sparse2, dim3(672), dim3(512), 0, stream,
                     audio, BhiT, BloT, coeffO, yedge, Ibuf);
  hipLaunchKernelGGL(espec, dim3(40, 32), dim3(256), 0, stream, Ibuf, Wmat, lut, ninst);
  hipLaunchKernelGGL(agc1, dim3(75), dim3(64), 0, stream, ninst, stl);
  hipLaunchKernelGGL(combine, dim3(79, 16), dim3(256), 0, stream, stl, gauss, stlL, stlR);
  hipLaunchKernelGGL(final_k, dim3(1), dim3(64), 0, stream, stlL, stlR, (float*)d_out);
}

// Round 8
// 364.468 us; speedup vs baseline: 1.8412x; 1.8412x over previous
//
#include <hip/hip_runtime.h>
#include <hip/hip_bf16.h>
#include <math.h>

#define T_LEN   320000
#define NB      16
#define NROWS   32          // 16 batch * 2 ch
#define NFRAMES 625
#define NCOMP   67
#define NCH     150
#define HOPSZ   512

typedef __attribute__((ext_vector_type(8))) short short8v;
typedef __attribute__((ext_vector_type(4))) float f32x4;

// per-window constants
__constant__ int cW_N[6]  = {2048,1024,512,256,128,64};
__constant__ int cW_K0[6] = {2,3,8,10,11,9};
__constant__ int cW_CB[7] = {0,4,17,29,40,46,67};
__constant__ int cW_CO[7] = {0,8192,21504,27648,30464,31232,32576};
// fused-coefficient geometry (per window)
__constant__ int dNEp[6]  = {3072,2048,1536,1280,1152,1152};
__constant__ int dNEr[6]  = {3072,2048,1536,1280,1152,1088};
__constant__ int dBTb[7]  = {0,147456,245760,319488,380928,436224,491520}; // [w][col=48][k=NEp] ushort
// init_fused chunk mapping
__constant__ int dCPB[6]  = {12,8,6,5,5,5};
__constant__ int dCKB[7]  = {0,48,152,224,279,309,414};
// edge task list
__constant__ int eW[8] = {0,0,0,1,2,3,4,5};
__constant__ int eF[8] = {0,1,624,0,0,0,0,0};

// ================= setup: tables + fused bf16 B + edge FIR, branch by blockIdx =================
// blocks [0,167): init_tables ; [167,581): init_fused ; [581,965): edge_y
__global__ __launch_bounds__(256) void setup_k(const float* __restrict__ h,
                                               const float* __restrict__ x,
                                               float2* __restrict__ coeff,
                                               float* __restrict__ Wmat,
                                               float* __restrict__ gauss,
                                               unsigned short* __restrict__ Bhi,
                                               unsigned short* __restrict__ Blo,
                                               float* __restrict__ ye) {
  __shared__ float sm[3585];
  const int bid = blockIdx.x, tid = threadIdx.x;
  if (bid < 167) {
    int gid = bid * 256 + tid;
    if (gid < 32576) {
      int w = 0;
      while (gid >= cW_CO[w + 1]) ++w;
      int local = gid - cW_CO[w];
      int N = cW_N[w];
      int jloc = local / N;
      int n = local - jloc * N;
      int k = cW_K0[w] + jloc;
      float win = 0.5f - 0.5f * cospif(2.0f * (float)n / (float)(N - 1));
      int r = (int)(((long long)k * (long long)n) % (long long)N);
      float ang = 2.0f * (float)r / (float)N;
      float scale = sqrtf(2.0f) / (0.5f * (float)(N - 1));
      float wc = win * scale;
      coeff[gid] = make_float2(wc * cospif(ang), wc * sinpif(ang));
    } else if (gid < 32576 + NCOMP * NCH) {
      int t = gid - 32576;
      int j = t / NCH, c = t - j * NCH;
      float erb = 1.75f + 0.25f * (float)c;
      float fc = (exp10f(erb * (1.0f / 21.366f)) - 1.0f) * (1.0f / 0.004368f);
      float erbw = 24.673f * (0.004368f * fc + 1.0f);
      float p = 4.0f * fc / erbw;
      int w = 0;
      while (j >= cW_CB[w + 1]) ++w;
      float freq = (float)(cW_K0[w] + (j - cW_CB[w])) * (32000.0f / (float)cW_N[w]);
      float g = fabsf(freq / fc - 1.0f);
      float pg = p * g;
      Wmat[j * NCH + c] = (1.0f + pg) * expf(-pg);
    } else if (gid == 32576 + NCOMP * NCH) {
      float tmp[17]; float s = 0.0f;
      for (int k = 0; k < 17; ++k) {
        float g = ((float)k - 8.0f) * 0.25f;
        tmp[k] = expf(-g * g / (2.0f * 0.08f * 0.08f));
        s += tmp[k];
      }
      for (int k = 0; k < 17; ++k) gauss[k] = tmp[k] / s;
    }
  } else if (bid < 581) {
    float* cre_l = sm;          // 1280
    float* cim_l = sm + 1280;   // 1280
    float* hs    = sm + 2560;   // 1025
    const int b2 = bid - 167;
    int w = 0;
    while (b2 >= dCKB[w + 1]) ++w;
    const int local = b2 - dCKB[w];
    const int jloc = local / dCPB[w];
    const int chunk = local - jloc * dCPB[w];
    const int N = cW_N[w];
    const int k = cW_K0[w] + jloc;
    const int NEp = dNEp[w], NEr = dNEr[w];
    const int v0 = chunk * 256;
    const int nlo_blk = max(0, v0 - 1024);
    const int nhi_blk = min(N - 1, v0 + 255);
    const int cnt_n = nhi_blk - nlo_blk + 1;
    const float scale = sqrtf(2.0f) / (0.5f * (float)(N - 1));
    for (int i = tid; i < 1025; i += 256) hs[i] = h[i];
    for (int i = tid; i < cnt_n; i += 256) {
      int n = nlo_blk + i;
      float win = 0.5f - 0.5f * cospif(2.0f * (float)n / (float)(N - 1));
      int r = (int)(((long long)k * (long long)n) % (long long)N);
      float ang = 2.0f * (float)r / (float)N;
      float wc = win * scale;
      cre_l[i] = wc * cospif(ang);
      cim_l[i] = wc * sinpif(ang);
    }
    __syncthreads();
    const int v = v0 + tid;
    if (v >= NEp) return;
    float re = 0.0f, im = 0.0f;
    if (v < NEr) {
      for (int n = nlo_blk; n <= nhi_blk; ++n) {
        int hidx = n + 1024 - v;
        if ((unsigned)hidx <= 1024u) {
          float hv = hs[hidx];
          re = fmaf(cre_l[n - nlo_blk], hv, re);
          im = fmaf(cim_l[n - nlo_blk], hv, im);
        }
      }
    }
    size_t o0 = (size_t)dBTb[w] + (size_t)(2 * jloc) * NEp + v;
    size_t o1 = o0 + NEp;
    unsigned ur = __float_as_uint(re);
    Bhi[o0] = (unsigned short)(ur >> 16);
    Blo[o0] = (unsigned short)(__float_as_uint(re - __uint_as_float(ur & 0xFFFF0000u)) >> 16);
    unsigned ui = __float_as_uint(im);
    Bhi[o1] = (unsigned short)(ui >> 16);
    Blo[o1] = (unsigned short)(__float_as_uint(im - __uint_as_float(ui & 0xFFFF0000u)) >> 16);
  } else {
    float* xl = sm;             // 1280
    float* hs = sm + 1280;      // 1025
    const int b2 = bid - 581;
    const int chunk = b2 % 12, row = b2 / 12;
    const size_t rowoff = (size_t)row * T_LEN;
    const int i0 = chunk * 256;
    const int pos0 = (i0 < 1536) ? i0 : 318464 + (i0 - 1536);
    for (int i = tid; i < 1025; i += 256) hs[i] = h[i];
    for (int i = tid; i < 1280; i += 256) {
      int g = pos0 - 512 + i;
      xl[i] = ((unsigned)g < (unsigned)T_LEN) ? x[rowoff + g] : 0.0f;
    }
    __syncthreads();
    // 4-way ILP on the serial FMA chain
    float a0 = 0.0f, a1 = 0.0f, a2 = 0.0f, a3 = 0.0f;
    const int d = tid + 1024;
    for (int m = 0; m < 1024; m += 4) {
      a0 = fmaf(hs[m],     xl[d - m],     a0);
      a1 = fmaf(hs[m + 1], xl[d - m - 1], a1);
      a2 = fmaf(hs[m + 2], xl[d - m - 2], a2);
      a3 = fmaf(hs[m + 3], xl[d - m - 3], a3);
    }
    float acc = ((a0 + a1) + (a2 + a3)) + hs[1024] * xl[d - 1024];
    ye[(size_t)row * 3072 + i0 + tid] = acc;
  }
}

// ================= MFMA fused FIR+DFT (+edge DFT blocks) =================
#define TILE_X 18944   // 31*512 + 3072
#define SWZ4(i) ((i) ^ ((((i) >> 9) & 15) << 3))

template<int W, int CT, int M0, int NM>
__device__ __forceinline__ void gemm_task(const unsigned short* sxh, const unsigned short* sxl,
                                          const unsigned short* __restrict__ Bhi,
                                          const unsigned short* __restrict__ Blo,
                                          float* __restrict__ Ibuf, int row, int f0, int lane) {
  constexpr int kNEp[6] = {3072,2048,1536,1280,1152,1152};
  constexpr int kStb[6] = {0,512,768,896,960,992};    // 1536 - (N+1024)/2
  constexpr int kNb[6]  = {4,13,12,11,6,21};
  constexpr int kJb0[6] = {0,4,17,29,40,46};
  constexpr int kBtb[6] = {0,147456,245760,319488,380928,436224};
  constexpr int NEp = kNEp[W], stb = kStb[W], nb = kNb[W], jb0 = kJb0[W];
  const int fidx = lane & 15, kg = lane >> 4;
  const unsigned short* Bh = Bhi + kBtb[W] + (size_t)((CT * 16 + fidx) * NEp + kg * 8);
  const unsigned short* Bl = Blo + kBtb[W] + (size_t)((CT * 16 + fidx) * NEp + kg * 8);
  const int ibase = fidx * 512 + stb + kg * 8;
  f32x4 acc[NM];
#pragma unroll
  for (int m = 0; m < NM; ++m) acc[m] = (f32x4){0.f, 0.f, 0.f, 0.f};
#pragma unroll 4
  for (int kk = 0; kk < NEp; kk += 32) {
    short8v bh = *(const short8v*)(Bh + kk);
    short8v bl = *(const short8v*)(Bl + kk);
#pragma unroll
    for (int m = 0; m < NM; ++m) {
      const int idx = SWZ4(ibase + (M0 + m) * 8192 + kk);
      short8v ah = *(const short8v*)(sxh + idx);
      short8v al = *(const short8v*)(sxl + idx);
      acc[m] = __builtin_amdgcn_mfma_f32_16x16x32_bf16(ah, bh, acc[m], 0, 0, 0);
      acc[m] = __builtin_amdgcn_mfma_f32_16x16x32_bf16(ah, bl, acc[m], 0, 0, 0);
      acc[m] = __builtin_amdgcn_mfma_f32_16x16x32_bf16(al, bh, acc[m], 0, 0, 0);
    }
  }
  const int col = CT * 16 + fidx;
#pragma unroll
  for (int m = 0; m < NM; ++m) {
#pragma unroll
    for (int r = 0; r < 4; ++r) {
      float v = acc[m][r];
      float sq = v * v;
      sq += __shfl_xor(sq, 1);
      int f = f0 + (M0 + m) * 16 + kg * 4 + r;
      if (!(col & 1)) {
        int j = col >> 1;
        bool edge = (f == 0) || (W == 0 && (f == 1 || f == 624));
        if (j < nb && f < NFRAMES && !edge)
          Ibuf[((size_t)row * NFRAMES + f) * NCOMP + jb0 + j] = sq;
      }
    }
  }
}

// blocks [0,640): MFMA gemm (fblk = b%20, row = b/20) ; [640,672): edge DFT (row = b-640)
__global__ __launch_bounds__(512) void sparse2(const float* __restrict__ x,
                                               const unsigned short* __restrict__ Bhi,
                                               const unsigned short* __restrict__ Blo,
                                               const float2* __restrict__ coeff,
                                               const float* __restrict__ ye,
                                               float* __restrict__ Ibuf) {
  __shared__ __align__(16) unsigned short sxh[TILE_X];
  __shared__ __align__(16) unsigned short sxl[TILE_X];
  const int b = blockIdx.x, tid = threadIdx.x;
  if (b < 640) {
    const int fblk = b % 20, row = b / 20;
    const int f0 = fblk * 32;
    const float* xr = x + (size_t)row * T_LEN;
    const int lo = f0 * HOPSZ - 1536;
    for (int i = 4 * tid; i < TILE_X; i += 2048) {
      const int g = lo + i;
      float v[4];
      if (g >= 0 && g + 4 <= T_LEN) {
        float4 p = *(const float4*)(xr + g);
        v[0] = p.x; v[1] = p.y; v[2] = p.z; v[3] = p.w;
      } else {
#pragma unroll
        for (int q = 0; q < 4; ++q) {
          int gg = g + q;
          v[q] = ((unsigned)gg < (unsigned)T_LEN) ? xr[gg] : 0.0f;
        }
      }
      unsigned short h4[4], l4[4];
#pragma unroll
      for (int q = 0; q < 4; ++q) {
        unsigned u = __float_as_uint(v[q]);
        h4[q] = (unsigned short)(u >> 16);
        float r = v[q] - __uint_as_float(u & 0xFFFF0000u);
        l4[q] = (unsigned short)(__float_as_uint(r) >> 16);
      }
      const int is = SWZ4(i);
      *(ushort4*)(sxh + is) = make_ushort4(h4[0], h4[1], h4[2], h4[3]);
      *(ushort4*)(sxl + is) = make_ushort4(l4[0], l4[1], l4[2], l4[3]);
    }
    __syncthreads();
    const int wv = tid >> 6, lane = tid & 63;
    // 11 column-tiles over 8 waves; every task keeps B-reuse across its M-tiles.
    switch (wv) {
      case 0: gemm_task<1,0,0,2>(sxh,sxl,Bhi,Blo,Ibuf,row,f0,lane); break;
      case 1: gemm_task<1,1,0,2>(sxh,sxl,Bhi,Blo,Ibuf,row,f0,lane); break;
      case 2: gemm_task<2,0,0,2>(sxh,sxl,Bhi,Blo,Ibuf,row,f0,lane);
              gemm_task<4,0,0,2>(sxh,sxl,Bhi,Blo,Ibuf,row,f0,lane); break;
      case 3: gemm_task<2,1,0,2>(sxh,sxl,Bhi,Blo,Ibuf,row,f0,lane);
              gemm_task<5,0,0,2>(sxh,sxl,Bhi,Blo,Ibuf,row,f0,lane); break;
      case 4: gemm_task<0,0,0,1>(sxh,sxl,Bhi,Blo,Ibuf,row,f0,lane);
              gemm_task<5,1,0,2>(sxh,sxl,Bhi,Blo,Ibuf,row,f0,lane); break;
      case 5: gemm_task<0,0,1,1>(sxh,sxl,Bhi,Blo,Ibuf,row,f0,lane);
              gemm_task<5,2,0,2>(sxh,sxl,Bhi,Blo,Ibuf,row,f0,lane); break;
      case 6: gemm_task<3,0,0,2>(sxh,sxl,Bhi,Blo,Ibuf,row,f0,lane); break;
      default: gemm_task<3,1,0,2>(sxh,sxl,Bhi,Blo,Ibuf,row,f0,lane); break;
    }
  } else {
    const int row = b - 640;
    float* yl = (float*)sxh;   // 12 KB alias
    for (int i = tid; i < 3072; i += 512) yl[i] = ye[(size_t)row * 3072 + i];
    __syncthreads();
    const int wv = tid >> 6, lane = tid & 63;
    const int w = eW[wv], f = eF[wv];
    const int N = cW_N[w];
    const int nb = cW_CB[w + 1] - cW_CB[w];
    for (int jl = 0; jl < nb; ++jl) {
      const float2* cf = coeff + cW_CO[w] + (size_t)jl * N;
      float re = 0.0f, im = 0.0f;
      for (int n = lane; n < N; n += 64) {
        int pos = f * HOPSZ - (N >> 1) + n;
        if ((unsigned)pos < (unsigned)T_LEN) {
          int yi = (pos < 1536) ? pos : (pos - 318464 + 1536);
          float yv = yl[yi];
          float2 cs = cf[n];
          re = fmaf(yv, cs.x, re);
          im = fmaf(yv, cs.y, im);
        }
      }
#pragma unroll
      for (int off = 32; off > 0; off >>= 1) {
        re += __shfl_xor(re, off);
        im += __shfl_xor(im, off);
      }
      if (lane == 0)
        Ibuf[((size_t)row * NFRAMES + f) * NCOMP + (cW_CB[w] + jl)] = re * re + im * im;
    }
  }
}

// ================= E = I@W -> dB -> LUT -> n_inst, 16 frames per block =================
__global__ __launch_bounds__(256) void espec(const float* __restrict__ Ibuf,
                                             const float* __restrict__ Wmat,
                                             const float* __restrict__ lut,
                                             float* __restrict__ ninst) {
  __shared__ float Is[16][68];
  __shared__ float luts[88];
  const int row = blockIdx.y;
  const int fb = blockIdx.x * 16;
  const int tid = threadIdx.x;
  if (tid < 88) luts[tid] = lut[tid];
  for (int u = tid; u < 16 * NCOMP; u += 256) {
    int fi = u / NCOMP, j = u - fi * NCOMP;
    int f = fb + fi;
    Is[fi][j] = (f < NFRAMES) ? Ibuf[((size_t)row * NFRAMES + f) * NCOMP + j] : 0.0f;
  }
  __syncthreads();
  for (int u = tid; u < 16 * NCH; u += 256) {
    int fi = u / NCH, c = u - fi * NCH;
    int f = fb + fi;
    if (f >= NFRAMES) continue;
    float e = 0.0f;
#pragma unroll 4
    for (int j = 0; j < NCOMP; ++j) e = fmaf(Is[fi][j], Wmat[j * NCH + c], e);
    float edb = 10.0f * log10f(e * 2.5e9f + 1e-12f);   // 1/I0 = 2.5e9
    float xv = fminf(fmaxf(edb, 0.0f), 110.0f);
    float u2 = xv * (87.0f / 110.0f);
    int i0 = (int)u2; if (i0 > 86) i0 = 86;
    float fr = u2 - (float)i0;
    float nv = fmaf(luts[i0 + 1] - luts[i0], fr, luts[i0]);
    ninst[((size_t)row * NFRAMES + f) * NCH + c] = nv;
  }
}

// ================= short-term AGC (8-deep pipelined, branch-free main loop) =================
__global__ __launch_bounds__(64) void agc1(const float* __restrict__ ninst,
                                           float* __restrict__ stl) {
  int idx = blockIdx.x * 64 + threadIdx.x;
  if (idx >= NROWS * NCH) return;
  int row = idx / NCH, c = idx - row * NCH;
  const float* src = ninst + (size_t)row * NFRAMES * NCH + c;
  float* dst = stl + (size_t)row * NFRAMES * NCH + c;
  float buf[8], cur[8];
#pragma unroll
  for (int i = 0; i < 8; ++i) buf[i] = src[(size_t)i * NCH];
  float s = 0.0f;
  // main: f = 0..615 ; prefetch f+8 (max 623) unconditional
  for (int fb = 0; fb < 616; fb += 8) {
#pragma unroll
    for (int i = 0; i < 8; ++i) cur[i] = buf[i];
#pragma unroll
    for (int i = 0; i < 8; ++i) buf[i] = src[(size_t)(fb + 8 + i) * NCH];
#pragma unroll
    for (int j = 0; j < 8; ++j) {
      float xv = cur[j];
      float a = (xv > s) ? 0.045f : 0.033f;
      s = a * xv + (1.0f - a) * s;
      dst[(size_t)(fb + j) * NCH] = s;
    }
  }
  // tail: f = 616..623 from buf, then 624 direct
#pragma unroll
  for (int j = 0; j < 8; ++j) {
    float xv = buf[j];
    float a = (xv > s) ? 0.045f : 0.033f;
    s = a * xv + (1.0f - a) * s;
    dst[(size_t)(616 + j) * NCH] = s;
  }
  float xv = src[(size_t)624 * NCH];
  float a = (xv > s) ? 0.045f : 0.033f;
  s = a * xv + (1.0f - a) * s;
  dst[(size_t)624 * NCH] = s;
}

// ================= ERB smoothing + binaural inhibition + channel sum, 8 frames/block =================
__global__ __launch_bounds__(256) void combine(const float* __restrict__ stl,
                                               const float* __restrict__ gauss,
                                               float* __restrict__ outL,
                                               float* __restrict__ outR) {
  __shared__ float sl[8][168], sr[8][168], gsh[17];
  const int b = blockIdx.y, fb = blockIdx.x * 8;
  const int tid = threadIdx.x;
  if (tid < 17) gsh[tid] = gauss[tid];
  for (int u = tid; u < 8 * 168; u += 256) {
    int fi = u / 168, c = u - fi * 168;
    sl[fi][c] = 0.0f; sr[fi][c] = 0.0f;
  }
  __syncthreads();
  for (int u = tid; u < 8 * 300; u += 256) {
    int fi = u / 300, r = u - fi * 300;
    int f = fb + fi;
    if (f < NFRAMES) {
      int ch = (r < NCH) ? 0 : 1;
      int c = (r < NCH) ? r : r - NCH;
      float v = stl[((size_t)(b * 2 + ch) * NFRAMES + f) * NCH + c];
      if (ch == 0) sl[fi][8 + c] = v; else sr[fi][8 + c] = v;
    }
  }
  __syncthreads();
  const int wv = tid >> 6, lane = tid & 63;
#pragma unroll
  for (int fi2 = 0; fi2 < 2; ++fi2) {
    const int fi = wv * 2 + fi2;
    const int f = fb + fi;
    float pvl = 0.0f, pvr = 0.0f;
#pragma unroll
    for (int s = 0; s < 3; ++s) {
      int c = lane + 64 * s;
      if (c < NCH) {
        float smL = 0.0f, smR = 0.0f;
#pragma unroll
        for (int t = 0; t < 17; ++t) {
          smL = fmaf(gsh[t], sl[fi][c + t], smL);
          smR = fmaf(gsh[t], sr[fi][c + t], smR);
        }
        pvl += smL / coshf(1.5978f * smR);
        pvr += smR / coshf(1.5978f * smL);
      }
    }
#pragma unroll
    for (int off = 32; off > 0; off >>= 1) {
      pvl += __shfl_xor(pvl, off);
      pvr += __shfl_xor(pvr, off);
    }
    if (lane == 0 && f < NFRAMES) {
      outL[b * NFRAMES + f] = pvl * 0.25f;
      outR[b * NFRAMES + f] = pvr * 0.25f;
    }
  }
}

// ================= long-term AGC + outputs: LDS-staged, 3-phase =================
__global__ __launch_bounds__(256) void final_k(const float* __restrict__ sLst,
                                               const float* __restrict__ sRst,
                                               float* __restrict__ out) {
  __shared__ float Ls[NB][641];   // padded stride: bank-conflict-free lane-per-batch reads
  __shared__ float Rs[NB][641];
  __shared__ float Lv[NB][641];
  const int tid = threadIdx.x;
  // phase 1: coalesced load + sOut
  for (int u = tid; u < NB * NFRAMES; u += 256) {
    int b = u / NFRAMES, f = u - b * NFRAMES;
    float a = sLst[u];
    float c = sRst[u];
    Ls[b][f] = a;
    Rs[b][f] = c;
    out[u] = a + c;                      // sLoud
  }
  __syncthreads();
  // phase 2: 16 lanes run the serial recurrence from LDS
  if (tid < NB) {
    const int b = tid;
    float ll = 0.0f, lr = 0.0f, mx = -3.4e38f;
    for (int f = 0; f < NFRAMES; ++f) {
      float a = Ls[b][f];
      float c = Rs[b][f];
      float aa = (a > ll) ? 0.01f : 0.00133f;
      ll = aa * a + (1.0f - aa) * ll;
      float ab = (c > lr) ? 0.01f : 0.00133f;
      lr = ab * c + (1.0f - ab) * lr;
      float lv = ll + lr;
      Lv[b][f] = lv;
      mx = fmaxf(mx, lv);
    }
    out[2 * NB * NFRAMES + b] = mx;      // mLoud
  }
  __syncthreads();
  // phase 3: coalesced lOut
  for (int u = tid; u < NB * NFRAMES; u += 256) {
    int b = u / NFRAMES, f = u - b * NFRAMES;
    out[NB * NFRAMES + u] = Lv[b][f];    // lLoud
  }
}

extern "C" void kernel_launch(void* const* d_in, const int* in_sizes, int n_in,
                              void* d_out, int out_size, void* d_ws, size_t ws_size,
                              hipStream_t stream) {
  const float* audio = (const float*)d_in[0];
  const float* ear   = (const float*)d_in[1];
  const float* lut   = (const float*)d_in[2];
  char* ws = (char*)d_ws;

  unsigned short* BhiT   = (unsigned short*)(ws);            //   983,040 B
  unsigned short* BloT   = (unsigned short*)(ws + 983040);   //   983,040 B
  float2*         coeffO = (float2*)(ws + 1966080);          //   260,608 B
  float*          Wmat   = (float*)(ws + 2226688);           //    40,200 B
  float*          gauss  = (float*)(ws + 2266888);           //        68 B
  float*          yedge  = (float*)(ws + 2266960);           //   393,216 B
  float*          Ibuf   = (float*)(ws + 2660176);           // 5,360,000 B
  float*          ninst  = (float*)(ws + 8020176);           // 12,000,000 B
  float*          stl    = (float*)(ws + 20020176);          // 12,000,000 B
  float*          stlL   = (float*)(ws + 32020176);          //    40,000 B
  float*          stlR   = (float*)(ws + 32060176);          //    40,000 B

  hipLaunchKernelGGL(setup_k, dim3(965), dim3(256), 0, stream,
                     ear, audio, coeffO, Wmat, gauss, BhiT, BloT, yedge);
  hipLaunchKernelGGL(sparse2, dim3(672), dim3(512), 0, stream,
                     audio, BhiT, BloT, coeffO, yedge, Ibuf);
  hipLaunchKernelGGL(espec, dim3(40, 32), dim3(256), 0, stream, Ibuf, Wmat, lut, ninst);
  hipLaunchKernelGGL(agc1, dim3(75), dim3(64), 0, stream, ninst, stl);
  hipLaunchKernelGGL(combine, dim3(79, 16), dim3(256), 0, stream, stl, gauss, stlL, stlR);
  hipLaunchKernelGGL(final_k, dim3(1), dim3(256), 0, stream, stlL, stlR, (float*)d_out);
}

// Round 9
// 348.579 us; speedup vs baseline: 1.9251x; 1.0456x over previous
//
#include <hip/hip_runtime.h>
#include <hip/hip_bf16.h>
#include <math.h>

#define T_LEN   320000
#define NB      16
#define NROWS   32          // 16 batch * 2 ch
#define NFRAMES 625
#define NCOMP   67
#define NCH     150
#define HOPSZ   512

typedef __attribute__((ext_vector_type(8))) short short8v;
typedef __attribute__((ext_vector_type(4))) float f32x4;

// per-window constants
__constant__ int cW_N[6]  = {2048,1024,512,256,128,64};
__constant__ int cW_K0[6] = {2,3,8,10,11,9};
__constant__ int cW_CB[7] = {0,4,17,29,40,46,67};
__constant__ int cW_CO[7] = {0,8192,21504,27648,30464,31232,32576};
// fused-coefficient geometry (per window)
__constant__ int dNEp[6]  = {3072,2048,1536,1280,1152,1152};
__constant__ int dNEr[6]  = {3072,2048,1536,1280,1152,1088};
__constant__ int dBTb[7]  = {0,147456,245760,319488,380928,436224,491520}; // [w][col=48][k=NEp] ushort
// init_fused chunk mapping
__constant__ int dCPB[6]  = {12,8,6,5,5,5};
__constant__ int dCKB[7]  = {0,48,152,224,279,309,414};
// edge task list
__constant__ int eW[8] = {0,0,0,1,2,3,4,5};
__constant__ int eF[8] = {0,1,624,0,0,0,0,0};

// ================= setup: tables + fused bf16 B + edge FIR, branch by blockIdx =================
// blocks [0,167): init_tables ; [167,581): init_fused ; [581,965): edge_y
__global__ __launch_bounds__(256) void setup_k(const float* __restrict__ h,
                                               const float* __restrict__ x,
                                               float2* __restrict__ coeff,
                                               float* __restrict__ Wmat,
                                               float* __restrict__ gauss,
                                               unsigned short* __restrict__ Bhi,
                                               unsigned short* __restrict__ Blo,
                                               float* __restrict__ ye) {
  __shared__ float sm[3585];
  const int bid = blockIdx.x, tid = threadIdx.x;
  if (bid < 167) {
    int gid = bid * 256 + tid;
    if (gid < 32576) {
      int w = 0;
      while (gid >= cW_CO[w + 1]) ++w;
      int local = gid - cW_CO[w];
      int N = cW_N[w];
      int jloc = local / N;
      int n = local - jloc * N;
      int k = cW_K0[w] + jloc;
      float win = 0.5f - 0.5f * cospif(2.0f * (float)n / (float)(N - 1));
      int r = (int)(((long long)k * (long long)n) % (long long)N);
      float ang = 2.0f * (float)r / (float)N;
      float scale = sqrtf(2.0f) / (0.5f * (float)(N - 1));
      float wc = win * scale;
      coeff[gid] = make_float2(wc * cospif(ang), wc * sinpif(ang));
    } else if (gid < 32576 + NCOMP * NCH) {
      int t = gid - 32576;
      int j = t / NCH, c = t - j * NCH;
      float erb = 1.75f + 0.25f * (float)c;
      float fc = (exp10f(erb * (1.0f / 21.366f)) - 1.0f) * (1.0f / 0.004368f);
      float erbw = 24.673f * (0.004368f * fc + 1.0f);
      float p = 4.0f * fc / erbw;
      int w = 0;
      while (j >= cW_CB[w + 1]) ++w;
      float freq = (float)(cW_K0[w] + (j - cW_CB[w])) * (32000.0f / (float)cW_N[w]);
      float g = fabsf(freq / fc - 1.0f);
      float pg = p * g;
      Wmat[j * NCH + c] = (1.0f + pg) * expf(-pg);
    } else if (gid == 32576 + NCOMP * NCH) {
      float tmp[17]; float s = 0.0f;
      for (int k = 0; k < 17; ++k) {
        float g = ((float)k - 8.0f) * 0.25f;
        tmp[k] = expf(-g * g / (2.0f * 0.08f * 0.08f));
        s += tmp[k];
      }
      for (int k = 0; k < 17; ++k) gauss[k] = tmp[k] / s;
    }
  } else if (bid < 581) {
    float* cre_l = sm;          // 1280
    float* cim_l = sm + 1280;   // 1280
    float* hs    = sm + 2560;   // 1025
    const int b2 = bid - 167;
    int w = 0;
    while (b2 >= dCKB[w + 1]) ++w;
    const int local = b2 - dCKB[w];
    const int jloc = local / dCPB[w];
    const int chunk = local - jloc * dCPB[w];
    const int N = cW_N[w];
    const int k = cW_K0[w] + jloc;
    const int NEp = dNEp[w], NEr = dNEr[w];
    const int v0 = chunk * 256;
    const int nlo_blk = max(0, v0 - 1024);
    const int nhi_blk = min(N - 1, v0 + 255);
    const int cnt_n = nhi_blk - nlo_blk + 1;
    const float scale = sqrtf(2.0f) / (0.5f * (float)(N - 1));
    for (int i = tid; i < 1025; i += 256) hs[i] = h[i];
    for (int i = tid; i < cnt_n; i += 256) {
      int n = nlo_blk + i;
      float win = 0.5f - 0.5f * cospif(2.0f * (float)n / (float)(N - 1));
      int r = (int)(((long long)k * (long long)n) % (long long)N);
      float ang = 2.0f * (float)r / (float)N;
      float wc = win * scale;
      cre_l[i] = wc * cospif(ang);
      cim_l[i] = wc * sinpif(ang);
    }
    __syncthreads();
    const int v = v0 + tid;
    if (v >= NEp) return;
    float re = 0.0f, im = 0.0f;
    if (v < NEr) {
      for (int n = nlo_blk; n <= nhi_blk; ++n) {
        int hidx = n + 1024 - v;
        if ((unsigned)hidx <= 1024u) {
          float hv = hs[hidx];
          re = fmaf(cre_l[n - nlo_blk], hv, re);
          im = fmaf(cim_l[n - nlo_blk], hv, im);
        }
      }
    }
    size_t o0 = (size_t)dBTb[w] + (size_t)(2 * jloc) * NEp + v;
    size_t o1 = o0 + NEp;
    unsigned ur = __float_as_uint(re);
    Bhi[o0] = (unsigned short)(ur >> 16);
    Blo[o0] = (unsigned short)(__float_as_uint(re - __uint_as_float(ur & 0xFFFF0000u)) >> 16);
    unsigned ui = __float_as_uint(im);
    Bhi[o1] = (unsigned short)(ui >> 16);
    Blo[o1] = (unsigned short)(__float_as_uint(im - __uint_as_float(ui & 0xFFFF0000u)) >> 16);
  } else {
    float* xl = sm;             // 1280
    float* hs = sm + 1280;      // 1025
    const int b2 = bid - 581;
    const int chunk = b2 % 12, row = b2 / 12;
    const size_t rowoff = (size_t)row * T_LEN;
    const int i0 = chunk * 256;
    const int pos0 = (i0 < 1536) ? i0 : 318464 + (i0 - 1536);
    for (int i = tid; i < 1025; i += 256) hs[i] = h[i];
    for (int i = tid; i < 1280; i += 256) {
      int g = pos0 - 512 + i;
      xl[i] = ((unsigned)g < (unsigned)T_LEN) ? x[rowoff + g] : 0.0f;
    }
    __syncthreads();
    // 4-way ILP on the serial FMA chain
    float a0 = 0.0f, a1 = 0.0f, a2 = 0.0f, a3 = 0.0f;
    const int d = tid + 1024;
    for (int m = 0; m < 1024; m += 4) {
      a0 = fmaf(hs[m],     xl[d - m],     a0);
      a1 = fmaf(hs[m + 1], xl[d - m - 1], a1);
      a2 = fmaf(hs[m + 2], xl[d - m - 2], a2);
      a3 = fmaf(hs[m + 3], xl[d - m - 3], a3);
    }
    float acc = ((a0 + a1) + (a2 + a3)) + hs[1024] * xl[d - 1024];
    ye[(size_t)row * 3072 + i0 + tid] = acc;
  }
}

// ================= MFMA fused FIR+DFT (+edge DFT blocks) =================
#define TILE_X 18944   // 31*512 + 3072
#define SWZ4(i) ((i) ^ ((((i) >> 9) & 15) << 3))

template<int W, int CT, int M0, int NM>
__device__ __forceinline__ void gemm_task(const unsigned short* sxh, const unsigned short* sxl,
                                          const unsigned short* __restrict__ Bhi,
                                          const unsigned short* __restrict__ Blo,
                                          float* __restrict__ Ibuf, int row, int f0, int lane) {
  constexpr int kNEp[6] = {3072,2048,1536,1280,1152,1152};
  constexpr int kStb[6] = {0,512,768,896,960,992};    // 1536 - (N+1024)/2
  constexpr int kNb[6]  = {4,13,12,11,6,21};
  constexpr int kJb0[6] = {0,4,17,29,40,46};
  constexpr int kBtb[6] = {0,147456,245760,319488,380928,436224};
  constexpr int NEp = kNEp[W], stb = kStb[W], nb = kNb[W], jb0 = kJb0[W];
  const int fidx = lane & 15, kg = lane >> 4;
  const unsigned short* Bh = Bhi + kBtb[W] + (size_t)((CT * 16 + fidx) * NEp + kg * 8);
  const unsigned short* Bl = Blo + kBtb[W] + (size_t)((CT * 16 + fidx) * NEp + kg * 8);
  const int ibase = fidx * 512 + stb + kg * 8;
  // 3 independent accumulator chains per M-tile: ah*bh, ah*bl, al*bh.
  f32x4 ahh[NM], ahl[NM], alh[NM];
#pragma unroll
  for (int m = 0; m < NM; ++m) {
    ahh[m] = (f32x4){0.f, 0.f, 0.f, 0.f};
    ahl[m] = (f32x4){0.f, 0.f, 0.f, 0.f};
    alh[m] = (f32x4){0.f, 0.f, 0.f, 0.f};
  }
#pragma unroll 4
  for (int kk = 0; kk < NEp; kk += 32) {
    short8v bh = *(const short8v*)(Bh + kk);
    short8v bl = *(const short8v*)(Bl + kk);
#pragma unroll
    for (int m = 0; m < NM; ++m) {
      const int idx = SWZ4(ibase + (M0 + m) * 8192 + kk);
      short8v ah = *(const short8v*)(sxh + idx);
      short8v al = *(const short8v*)(sxl + idx);
      ahh[m] = __builtin_amdgcn_mfma_f32_16x16x32_bf16(ah, bh, ahh[m], 0, 0, 0);
      ahl[m] = __builtin_amdgcn_mfma_f32_16x16x32_bf16(ah, bl, ahl[m], 0, 0, 0);
      alh[m] = __builtin_amdgcn_mfma_f32_16x16x32_bf16(al, bh, alh[m], 0, 0, 0);
    }
  }
  const int col = CT * 16 + fidx;
#pragma unroll
  for (int m = 0; m < NM; ++m) {
#pragma unroll
    for (int r = 0; r < 4; ++r) {
      float v = (ahh[m][r] + ahl[m][r]) + alh[m][r];
      float sq = v * v;
      sq += __shfl_xor(sq, 1);
      int f = f0 + (M0 + m) * 16 + kg * 4 + r;
      if (!(col & 1)) {
        int j = col >> 1;
        bool edge = (f == 0) || (W == 0 && (f == 1 || f == 624));
        if (j < nb && f < NFRAMES && !edge)
          Ibuf[((size_t)row * NFRAMES + f) * NCOMP + jb0 + j] = sq;
      }
    }
  }
}

// blocks [0,640): MFMA gemm (fblk = b%20, row = b/20) ; [640,672): edge DFT (row = b-640)
__global__ __launch_bounds__(512) void sparse2(const float* __restrict__ x,
                                               const unsigned short* __restrict__ Bhi,
                                               const unsigned short* __restrict__ Blo,
                                               const float2* __restrict__ coeff,
                                               const float* __restrict__ ye,
                                               float* __restrict__ Ibuf) {
  __shared__ __align__(16) unsigned short sxh[TILE_X];
  __shared__ __align__(16) unsigned short sxl[TILE_X];
  const int b = blockIdx.x, tid = threadIdx.x;
  if (b < 640) {
    const int fblk = b % 20, row = b / 20;
    const int f0 = fblk * 32;
    const float* xr = x + (size_t)row * T_LEN;
    const int lo = f0 * HOPSZ - 1536;
    for (int i = 4 * tid; i < TILE_X; i += 2048) {
      const int g = lo + i;
      float v[4];
      if (g >= 0 && g + 4 <= T_LEN) {
        float4 p = *(const float4*)(xr + g);
        v[0] = p.x; v[1] = p.y; v[2] = p.z; v[3] = p.w;
      } else {
#pragma unroll
        for (int q = 0; q < 4; ++q) {
          int gg = g + q;
          v[q] = ((unsigned)gg < (unsigned)T_LEN) ? xr[gg] : 0.0f;
        }
      }
      unsigned short h4[4], l4[4];
#pragma unroll
      for (int q = 0; q < 4; ++q) {
        unsigned u = __float_as_uint(v[q]);
        h4[q] = (unsigned short)(u >> 16);
        float r = v[q] - __uint_as_float(u & 0xFFFF0000u);
        l4[q] = (unsigned short)(__float_as_uint(r) >> 16);
      }
      const int is = SWZ4(i);
      *(ushort4*)(sxh + is) = make_ushort4(h4[0], h4[1], h4[2], h4[3]);
      *(ushort4*)(sxl + is) = make_ushort4(l4[0], l4[1], l4[2], l4[3]);
    }
    __syncthreads();
    const int wv = tid >> 6, lane = tid & 63;
    // 11 column-tiles over 8 waves; every task keeps B-reuse across its M-tiles.
    switch (wv) {
      case 0: gemm_task<1,0,0,2>(sxh,sxl,Bhi,Blo,Ibuf,row,f0,lane); break;
      case 1: gemm_task<1,1,0,2>(sxh,sxl,Bhi,Blo,Ibuf,row,f0,lane); break;
      case 2: gemm_task<2,0,0,2>(sxh,sxl,Bhi,Blo,Ibuf,row,f0,lane);
              gemm_task<4,0,0,2>(sxh,sxl,Bhi,Blo,Ibuf,row,f0,lane); break;
      case 3: gemm_task<2,1,0,2>(sxh,sxl,Bhi,Blo,Ibuf,row,f0,lane);
              gemm_task<5,0,0,2>(sxh,sxl,Bhi,Blo,Ibuf,row,f0,lane); break;
      case 4: gemm_task<0,0,0,1>(sxh,sxl,Bhi,Blo,Ibuf,row,f0,lane);
              gemm_task<5,1,0,2>(sxh,sxl,Bhi,Blo,Ibuf,row,f0,lane); break;
      case 5: gemm_task<0,0,1,1>(sxh,sxl,Bhi,Blo,Ibuf,row,f0,lane);
              gemm_task<5,2,0,2>(sxh,sxl,Bhi,Blo,Ibuf,row,f0,lane); break;
      case 6: gemm_task<3,0,0,2>(sxh,sxl,Bhi,Blo,Ibuf,row,f0,lane); break;
      default: gemm_task<3,1,0,2>(sxh,sxl,Bhi,Blo,Ibuf,row,f0,lane); break;
    }
  } else {
    const int row = b - 640;
    float* yl = (float*)sxh;   // 12 KB alias
    for (int i = tid; i < 3072; i += 512) yl[i] = ye[(size_t)row * 3072 + i];
    __syncthreads();
    const int wv = tid >> 6, lane = tid & 63;
    const int w = eW[wv], f = eF[wv];
    const int N = cW_N[w];
    const int nb = cW_CB[w + 1] - cW_CB[w];
    for (int jl = 0; jl < nb; ++jl) {
      const float2* cf = coeff + cW_CO[w] + (size_t)jl * N;
      float re = 0.0f, im = 0.0f;
      for (int n = lane; n < N; n += 64) {
        int pos = f * HOPSZ - (N >> 1) + n;
        if ((unsigned)pos < (unsigned)T_LEN) {
          int yi = (pos < 1536) ? pos : (pos - 318464 + 1536);
          float yv = yl[yi];
          float2 cs = cf[n];
          re = fmaf(yv, cs.x, re);
          im = fmaf(yv, cs.y, im);
        }
      }
#pragma unroll
      for (int off = 32; off > 0; off >>= 1) {
        re += __shfl_xor(re, off);
        im += __shfl_xor(im, off);
      }
      if (lane == 0)
        Ibuf[((size_t)row * NFRAMES + f) * NCOMP + (cW_CB[w] + jl)] = re * re + im * im;
    }
  }
}

// ================= E = I@W -> dB -> LUT -> n_inst, 16 frames per block =================
__global__ __launch_bounds__(256) void espec(const float* __restrict__ Ibuf,
                                             const float* __restrict__ Wmat,
                                             const float* __restrict__ lut,
                                             float* __restrict__ ninst) {
  __shared__ float Is[16][68];
  __shared__ float luts[88];
  const int row = blockIdx.y;
  const int fb = blockIdx.x * 16;
  const int tid = threadIdx.x;
  if (tid < 88) luts[tid] = lut[tid];
  for (int u = tid; u < 16 * NCOMP; u += 256) {
    int fi = u / NCOMP, j = u - fi * NCOMP;
    int f = fb + fi;
    Is[fi][j] = (f < NFRAMES) ? Ibuf[((size_t)row * NFRAMES + f) * NCOMP + j] : 0.0f;
  }
  __syncthreads();
  for (int u = tid; u < 16 * NCH; u += 256) {
    int fi = u / NCH, c = u - fi * NCH;
    int f = fb + fi;
    if (f >= NFRAMES) continue;
    float e = 0.0f;
#pragma unroll 4
    for (int j = 0; j < NCOMP; ++j) e = fmaf(Is[fi][j], Wmat[j * NCH + c], e);
    float edb = 10.0f * log10f(e * 2.5e9f + 1e-12f);   // 1/I0 = 2.5e9
    float xv = fminf(fmaxf(edb, 0.0f), 110.0f);
    float u2 = xv * (87.0f / 110.0f);
    int i0 = (int)u2; if (i0 > 86) i0 = 86;
    float fr = u2 - (float)i0;
    float nv = fmaf(luts[i0 + 1] - luts[i0], fr, luts[i0]);
    ninst[((size_t)row * NFRAMES + f) * NCH + c] = nv;
  }
}

// ================= short-term AGC (16-deep pipelined, branch-free main loop) =================
__global__ __launch_bounds__(64) void agc1(const float* __restrict__ ninst,
                                           float* __restrict__ stl) {
  int idx = blockIdx.x * 64 + threadIdx.x;
  if (idx >= NROWS * NCH) return;
  int row = idx / NCH, c = idx - row * NCH;
  const float* src = ninst + (size_t)row * NFRAMES * NCH + c;
  float* dst = stl + (size_t)row * NFRAMES * NCH + c;
  float buf[16], cur[16];
#pragma unroll
  for (int i = 0; i < 16; ++i) buf[i] = src[(size_t)i * NCH];
  float s = 0.0f;
  // main: f = 0..607 ; prefetch f+16 (max 623) unconditional
  for (int fb = 0; fb < 608; fb += 16) {
#pragma unroll
    for (int i = 0; i < 16; ++i) cur[i] = buf[i];
#pragma unroll
    for (int i = 0; i < 16; ++i) buf[i] = src[(size_t)(fb + 16 + i) * NCH];
#pragma unroll
    for (int j = 0; j < 16; ++j) {
      float xv = cur[j];
      float a = (xv > s) ? 0.045f : 0.033f;
      s = a * xv + (1.0f - a) * s;
      dst[(size_t)(fb + j) * NCH] = s;
    }
  }
  // tail: f = 608..623 from buf, then 624 direct
#pragma unroll
  for (int j = 0; j < 16; ++j) {
    float xv = buf[j];
    float a = (xv > s) ? 0.045f : 0.033f;
    s = a * xv + (1.0f - a) * s;
    dst[(size_t)(608 + j) * NCH] = s;
  }
  float xv = src[(size_t)624 * NCH];
  float a = (xv > s) ? 0.045f : 0.033f;
  s = a * xv + (1.0f - a) * s;
  dst[(size_t)624 * NCH] = s;
}

// ================= ERB smoothing + binaural inhibition + channel sum, 8 frames/block =================
__global__ __launch_bounds__(256) void combine(const float* __restrict__ stl,
                                               const float* __restrict__ gauss,
                                               float* __restrict__ outL,
                                               float* __restrict__ outR) {
  __shared__ float sl[8][168], sr[8][168], gsh[17];
  const int b = blockIdx.y, fb = blockIdx.x * 8;
  const int tid = threadIdx.x;
  if (tid < 17) gsh[tid] = gauss[tid];
  for (int u = tid; u < 8 * 168; u += 256) {
    int fi = u / 168, c = u - fi * 168;
    sl[fi][c] = 0.0f; sr[fi][c] = 0.0f;
  }
  __syncthreads();
  for (int u = tid; u < 8 * 300; u += 256) {
    int fi = u / 300, r = u - fi * 300;
    int f = fb + fi;
    if (f < NFRAMES) {
      int ch = (r < NCH) ? 0 : 1;
      int c = (r < NCH) ? r : r - NCH;
      float v = stl[((size_t)(b * 2 + ch) * NFRAMES + f) * NCH + c];
      if (ch == 0) sl[fi][8 + c] = v; else sr[fi][8 + c] = v;
    }
  }
  __syncthreads();
  const int wv = tid >> 6, lane = tid & 63;
#pragma unroll
  for (int fi2 = 0; fi2 < 2; ++fi2) {
    const int fi = wv * 2 + fi2;
    const int f = fb + fi;
    float pvl = 0.0f, pvr = 0.0f;
#pragma unroll
    for (int s = 0; s < 3; ++s) {
      int c = lane + 64 * s;
      if (c < NCH) {
        float smL = 0.0f, smR = 0.0f;
#pragma unroll
        for (int t = 0; t < 17; ++t) {
          smL = fmaf(gsh[t], sl[fi][c + t], smL);
          smR = fmaf(gsh[t], sr[fi][c + t], smR);
        }
        // sech(z) = 2t/(1+t^2), t = e^-z  (z >= 0 here)
        float tR = __expf(-1.5978f * smR);
        float tL = __expf(-1.5978f * smL);
        pvl += smL * (2.0f * tR / fmaf(tR, tR, 1.0f));
        pvr += smR * (2.0f * tL / fmaf(tL, tL, 1.0f));
      }
    }
#pragma unroll
    for (int off = 32; off > 0; off >>= 1) {
      pvl += __shfl_xor(pvl, off);
      pvr += __shfl_xor(pvr, off);
    }
    if (lane == 0 && f < NFRAMES) {
      outL[b * NFRAMES + f] = pvl * 0.25f;
      outR[b * NFRAMES + f] = pvr * 0.25f;
    }
  }
}

// ================= long-term AGC + outputs: LDS-staged, 3-phase =================
__global__ __launch_bounds__(256) void final_k(const float* __restrict__ sLst,
                                               const float* __restrict__ sRst,
                                               float* __restrict__ out) {
  __shared__ float Ls[NB][641];   // padded stride: bank-conflict-free lane-per-batch reads
  __shared__ float Rs[NB][641];
  __shared__ float Lv[NB][641];
  const int tid = threadIdx.x;
  // phase 1: coalesced load + sOut
  for (int u = tid; u < NB * NFRAMES; u += 256) {
    int b = u / NFRAMES, f = u - b * NFRAMES;
    float a = sLst[u];
    float c = sRst[u];
    Ls[b][f] = a;
    Rs[b][f] = c;
    out[u] = a + c;                      // sLoud
  }
  __syncthreads();
  // phase 2: 16 lanes run the serial recurrence from LDS
  if (tid < NB) {
    const int b = tid;
    float ll = 0.0f, lr = 0.0f, mx = -3.4e38f;
    for (int f = 0; f < NFRAMES; ++f) {
      float a = Ls[b][f];
      float c = Rs[b][f];
      float aa = (a > ll) ? 0.01f : 0.00133f;
      ll = aa * a + (1.0f - aa) * ll;
      float ab = (c > lr) ? 0.01f : 0.00133f;
      lr = ab * c + (1.0f - ab) * lr;
      float lv = ll + lr;
      Lv[b][f] = lv;
      mx = fmaxf(mx, lv);
    }
    out[2 * NB * NFRAMES + b] = mx;      // mLoud
  }
  __syncthreads();
  // phase 3: coalesced lOut
  for (int u = tid; u < NB * NFRAMES; u += 256) {
    int b = u / NFRAMES, f = u - b * NFRAMES;
    out[NB * NFRAMES + u] = Lv[b][f];    // lLoud
  }
}

extern "C" void kernel_launch(void* const* d_in, const int* in_sizes, int n_in,
                              void* d_out, int out_size, void* d_ws, size_t ws_size,
                              hipStream_t stream) {
  const float* audio = (const float*)d_in[0];
  const float* ear   = (const float*)d_in[1];
  const float* lut   = (const float*)d_in[2];
  char* ws = (char*)d_ws;

  unsigned short* BhiT   = (unsigned short*)(ws);            //   983,040 B
  unsigned short* BloT   = (unsigned short*)(ws + 983040);   //   983,040 B
  float2*         coeffO = (float2*)(ws + 1966080);          //   260,608 B
  float*          Wmat   = (float*)(ws + 2226688);           //    40,200 B
  float*          gauss  = (float*)(ws + 2266888);           //        68 B
  float*          yedge  = (float*)(ws + 2266960);           //   393,216 B
  float*          Ibuf   = (float*)(ws + 2660176);           // 5,360,000 B
  float*          ninst  = (float*)(ws + 8020176);           // 12,000,000 B
  float*          stl    = (float*)(ws + 20020176);          // 12,000,000 B
  float*          stlL   = (float*)(ws + 32020176);          //    40,000 B
  float*          stlR   = (float*)(ws + 32060176);          //    40,000 B

  hipLaunchKernelGGL(setup_k, dim3(965), dim3(256), 0, stream,
                     ear, audio, coeffO, Wmat, gauss, BhiT, BloT, yedge);
  hipLaunchKernelGGL(sparse2, dim3(672), dim3(512), 0, stream,
                     audio, BhiT, BloT, coeffO, yedge, Ibuf);
  hipLaunchKernelGGL(espec, dim3(40, 32), dim3(256), 0, stream, Ibuf, Wmat, lut, ninst);
  hipLaunchKernelGGL(agc1, dim3(75), dim3(64), 0, stream, ninst, stl);
  hipLaunchKernelGGL(combine, dim3(79, 16), dim3(256), 0, stream, stl, gauss, stlL, stlR);
  hipLaunchKernelGGL(final_k, dim3(1), dim3(256), 0, stream, stlL, stlR, (float*)d_out);
}

// Round 10
// 346.008 us; speedup vs baseline: 1.9394x; 1.0074x over previous
//
#include <hip/hip_runtime.h>
#include <hip/hip_bf16.h>
#include <math.h>

#define T_LEN   320000
#define NB      16
#define NROWS   32          // 16 batch * 2 ch
#define NFRAMES 625
#define NCOMP   67
#define NCH     150
#define HOPSZ   512

typedef __attribute__((ext_vector_type(8))) short short8v;
typedef __attribute__((ext_vector_type(4))) float f32x4;

// per-window constants
__constant__ int cW_N[6]  = {2048,1024,512,256,128,64};
__constant__ int cW_K0[6] = {2,3,8,10,11,9};
__constant__ int cW_CB[7] = {0,4,17,29,40,46,67};
__constant__ int cW_CO[7] = {0,8192,21504,27648,30464,31232,32576};
// fused-coefficient geometry (per window)
__constant__ int dNEp[6]  = {3072,2048,1536,1280,1152,1152};
__constant__ int dNEr[6]  = {3072,2048,1536,1280,1152,1088};
__constant__ int dBTb[7]  = {0,147456,245760,319488,380928,436224,491520}; // [w][col=48][k=NEp] ushort
// init_fused chunk mapping
__constant__ int dCPB[6]  = {12,8,6,5,5,5};
__constant__ int dCKB[7]  = {0,48,152,224,279,309,414};
// edge task list
__constant__ int eW[8] = {0,0,0,1,2,3,4,5};
__constant__ int eF[8] = {0,1,624,0,0,0,0,0};

// ================= setup: tables + fused bf16 B + edge FIR, branch by blockIdx =================
// blocks [0,167): init_tables ; [167,581): init_fused ; [581,965): edge_y
__global__ __launch_bounds__(256) void setup_k(const float* __restrict__ h,
                                               const float* __restrict__ x,
                                               float2* __restrict__ coeff,
                                               float* __restrict__ Wmat,
                                               float* __restrict__ gauss,
                                               unsigned short* __restrict__ Bhi,
                                               unsigned short* __restrict__ Blo,
                                               float* __restrict__ ye) {
  __shared__ float sm[3585];
  const int bid = blockIdx.x, tid = threadIdx.x;
  if (bid < 167) {
    int gid = bid * 256 + tid;
    if (gid < 32576) {
      int w = 0;
      while (gid >= cW_CO[w + 1]) ++w;
      int local = gid - cW_CO[w];
      int N = cW_N[w];
      int jloc = local / N;
      int n = local - jloc * N;
      int k = cW_K0[w] + jloc;
      float win = 0.5f - 0.5f * cospif(2.0f * (float)n / (float)(N - 1));
      int r = (int)(((long long)k * (long long)n) % (long long)N);
      float ang = 2.0f * (float)r / (float)N;
      float scale = sqrtf(2.0f) / (0.5f * (float)(N - 1));
      float wc = win * scale;
      coeff[gid] = make_float2(wc * cospif(ang), wc * sinpif(ang));
    } else if (gid < 32576 + NCOMP * NCH) {
      int t = gid - 32576;
      int j = t / NCH, c = t - j * NCH;
      float erb = 1.75f + 0.25f * (float)c;
      float fc = (exp10f(erb * (1.0f / 21.366f)) - 1.0f) * (1.0f / 0.004368f);
      float erbw = 24.673f * (0.004368f * fc + 1.0f);
      float p = 4.0f * fc / erbw;
      int w = 0;
      while (j >= cW_CB[w + 1]) ++w;
      float freq = (float)(cW_K0[w] + (j - cW_CB[w])) * (32000.0f / (float)cW_N[w]);
      float g = fabsf(freq / fc - 1.0f);
      float pg = p * g;
      Wmat[j * NCH + c] = (1.0f + pg) * expf(-pg);
    } else if (gid == 32576 + NCOMP * NCH) {
      float tmp[17]; float s = 0.0f;
      for (int k = 0; k < 17; ++k) {
        float g = ((float)k - 8.0f) * 0.25f;
        tmp[k] = expf(-g * g / (2.0f * 0.08f * 0.08f));
        s += tmp[k];
      }
      for (int k = 0; k < 17; ++k) gauss[k] = tmp[k] / s;
    }
  } else if (bid < 581) {
    float* cre_l = sm;          // 1280
    float* cim_l = sm + 1280;   // 1280
    float* hs    = sm + 2560;   // 1025
    const int b2 = bid - 167;
    int w = 0;
    while (b2 >= dCKB[w + 1]) ++w;
    const int local = b2 - dCKB[w];
    const int jloc = local / dCPB[w];
    const int chunk = local - jloc * dCPB[w];
    const int N = cW_N[w];
    const int k = cW_K0[w] + jloc;
    const int NEp = dNEp[w], NEr = dNEr[w];
    const int v0 = chunk * 256;
    const int nlo_blk = max(0, v0 - 1024);
    const int nhi_blk = min(N - 1, v0 + 255);
    const int cnt_n = nhi_blk - nlo_blk + 1;
    const float scale = sqrtf(2.0f) / (0.5f * (float)(N - 1));
    for (int i = tid; i < 1025; i += 256) hs[i] = h[i];
    for (int i = tid; i < cnt_n; i += 256) {
      int n = nlo_blk + i;
      float win = 0.5f - 0.5f * cospif(2.0f * (float)n / (float)(N - 1));
      int r = (int)(((long long)k * (long long)n) % (long long)N);
      float ang = 2.0f * (float)r / (float)N;
      float wc = win * scale;
      cre_l[i] = wc * cospif(ang);
      cim_l[i] = wc * sinpif(ang);
    }
    __syncthreads();
    const int v = v0 + tid;
    if (v >= NEp) return;
    float re = 0.0f, im = 0.0f;
    if (v < NEr) {
      for (int n = nlo_blk; n <= nhi_blk; ++n) {
        int hidx = n + 1024 - v;
        if ((unsigned)hidx <= 1024u) {
          float hv = hs[hidx];
          re = fmaf(cre_l[n - nlo_blk], hv, re);
          im = fmaf(cim_l[n - nlo_blk], hv, im);
        }
      }
    }
    size_t o0 = (size_t)dBTb[w] + (size_t)(2 * jloc) * NEp + v;
    size_t o1 = o0 + NEp;
    unsigned ur = __float_as_uint(re);
    Bhi[o0] = (unsigned short)(ur >> 16);
    Blo[o0] = (unsigned short)(__float_as_uint(re - __uint_as_float(ur & 0xFFFF0000u)) >> 16);
    unsigned ui = __float_as_uint(im);
    Bhi[o1] = (unsigned short)(ui >> 16);
    Blo[o1] = (unsigned short)(__float_as_uint(im - __uint_as_float(ui & 0xFFFF0000u)) >> 16);
  } else {
    float* xl = sm;             // 1280
    float* hs = sm + 1280;      // 1025
    const int b2 = bid - 581;
    const int chunk = b2 % 12, row = b2 / 12;
    const size_t rowoff = (size_t)row * T_LEN;
    const int i0 = chunk * 256;
    const int pos0 = (i0 < 1536) ? i0 : 318464 + (i0 - 1536);
    for (int i = tid; i < 1025; i += 256) hs[i] = h[i];
    for (int i = tid; i < 1280; i += 256) {
      int g = pos0 - 512 + i;
      xl[i] = ((unsigned)g < (unsigned)T_LEN) ? x[rowoff + g] : 0.0f;
    }
    __syncthreads();
    // 4-way ILP on the serial FMA chain
    float a0 = 0.0f, a1 = 0.0f, a2 = 0.0f, a3 = 0.0f;
    const int d = tid + 1024;
    for (int m = 0; m < 1024; m += 4) {
      a0 = fmaf(hs[m],     xl[d - m],     a0);
      a1 = fmaf(hs[m + 1], xl[d - m - 1], a1);
      a2 = fmaf(hs[m + 2], xl[d - m - 2], a2);
      a3 = fmaf(hs[m + 3], xl[d - m - 3], a3);
    }
    float acc = ((a0 + a1) + (a2 + a3)) + hs[1024] * xl[d - 1024];
    ye[(size_t)row * 3072 + i0 + tid] = acc;
  }
}

// ================= MFMA fused FIR+DFT (+edge DFT blocks) =================
#define TILE_X 18944   // 31*512 + 3072
#define SWZ4(i) ((i) ^ ((((i) >> 9) & 15) << 3))

// Group-prefetched GEMM task: 4 k-steps (128 k) per group, all 8 B fragments
// loaded into registers before the compute phase -> one latency exposure per
// group instead of per k-step.
template<int W, int CT, int M0, int NM>
__device__ __forceinline__ void gemm_task(const unsigned short* sxh, const unsigned short* sxl,
                                          const unsigned short* __restrict__ Bhi,
                                          const unsigned short* __restrict__ Blo,
                                          float* __restrict__ Ibuf, int row, int f0, int lane) {
  constexpr int kNEp[6] = {3072,2048,1536,1280,1152,1152};
  constexpr int kStb[6] = {0,512,768,896,960,992};    // 1536 - (N+1024)/2
  constexpr int kNb[6]  = {4,13,12,11,6,21};
  constexpr int kJb0[6] = {0,4,17,29,40,46};
  constexpr int kBtb[6] = {0,147456,245760,319488,380928,436224};
  constexpr int NEp = kNEp[W], stb = kStb[W], nb = kNb[W], jb0 = kJb0[W];
  const int fidx = lane & 15, kg = lane >> 4;
  const unsigned short* Bh = Bhi + kBtb[W] + (size_t)((CT * 16 + fidx) * NEp + kg * 8);
  const unsigned short* Bl = Blo + kBtb[W] + (size_t)((CT * 16 + fidx) * NEp + kg * 8);
  const int ibase = fidx * 512 + stb + kg * 8;
  f32x4 ahh[NM], ahl[NM], alh[NM];
#pragma unroll
  for (int m = 0; m < NM; ++m) {
    ahh[m] = (f32x4){0.f, 0.f, 0.f, 0.f};
    ahl[m] = (f32x4){0.f, 0.f, 0.f, 0.f};
    alh[m] = (f32x4){0.f, 0.f, 0.f, 0.f};
  }
  for (int kk0 = 0; kk0 < NEp; kk0 += 128) {
    // phase 1: prefetch 8 B fragments (static reg array)
    short8v bhv[4], blv[4];
#pragma unroll
    for (int q = 0; q < 4; ++q) {
      bhv[q] = *(const short8v*)(Bh + kk0 + 32 * q);
      blv[q] = *(const short8v*)(Bl + kk0 + 32 * q);
    }
    // phase 2: compute 4 k-steps from LDS + registers
#pragma unroll
    for (int q = 0; q < 4; ++q) {
#pragma unroll
      for (int m = 0; m < NM; ++m) {
        const int idx = SWZ4(ibase + (M0 + m) * 8192 + kk0 + 32 * q);
        short8v ah = *(const short8v*)(sxh + idx);
        short8v al = *(const short8v*)(sxl + idx);
        ahh[m] = __builtin_amdgcn_mfma_f32_16x16x32_bf16(ah, bhv[q], ahh[m], 0, 0, 0);
        ahl[m] = __builtin_amdgcn_mfma_f32_16x16x32_bf16(ah, blv[q], ahl[m], 0, 0, 0);
        alh[m] = __builtin_amdgcn_mfma_f32_16x16x32_bf16(al, bhv[q], alh[m], 0, 0, 0);
      }
    }
  }
  const int col = CT * 16 + fidx;
#pragma unroll
  for (int m = 0; m < NM; ++m) {
#pragma unroll
    for (int r = 0; r < 4; ++r) {
      float v = (ahh[m][r] + ahl[m][r]) + alh[m][r];
      float sq = v * v;
      sq += __shfl_xor(sq, 1);
      int f = f0 + (M0 + m) * 16 + kg * 4 + r;
      if (!(col & 1)) {
        int j = col >> 1;
        bool edge = (f == 0) || (W == 0 && (f == 1 || f == 624));
        if (j < nb && f < NFRAMES && !edge)
          Ibuf[((size_t)row * NFRAMES + f) * NCOMP + jb0 + j] = sq;
      }
    }
  }
}

// blocks [0,640): MFMA gemm (fblk = b%20, row = b/20) ; [640,672): edge DFT (row = b-640)
__global__ __launch_bounds__(512) void sparse2(const float* __restrict__ x,
                                               const unsigned short* __restrict__ Bhi,
                                               const unsigned short* __restrict__ Blo,
                                               const float2* __restrict__ coeff,
                                               const float* __restrict__ ye,
                                               float* __restrict__ Ibuf) {
  __shared__ __align__(16) unsigned short sxh[TILE_X];
  __shared__ __align__(16) unsigned short sxl[TILE_X];
  const int b = blockIdx.x, tid = threadIdx.x;
  if (b < 640) {
    const int fblk = b % 20, row = b / 20;
    const int f0 = fblk * 32;
    const float* xr = x + (size_t)row * T_LEN;
    const int lo = f0 * HOPSZ - 1536;
    for (int i = 4 * tid; i < TILE_X; i += 2048) {
      const int g = lo + i;
      float v[4];
      if (g >= 0 && g + 4 <= T_LEN) {
        float4 p = *(const float4*)(xr + g);
        v[0] = p.x; v[1] = p.y; v[2] = p.z; v[3] = p.w;
      } else {
#pragma unroll
        for (int q = 0; q < 4; ++q) {
          int gg = g + q;
          v[q] = ((unsigned)gg < (unsigned)T_LEN) ? xr[gg] : 0.0f;
        }
      }
      unsigned short h4[4], l4[4];
#pragma unroll
      for (int q = 0; q < 4; ++q) {
        unsigned u = __float_as_uint(v[q]);
        h4[q] = (unsigned short)(u >> 16);
        float r = v[q] - __uint_as_float(u & 0xFFFF0000u);
        l4[q] = (unsigned short)(__float_as_uint(r) >> 16);
      }
      const int is = SWZ4(i);
      *(ushort4*)(sxh + is) = make_ushort4(h4[0], h4[1], h4[2], h4[3]);
      *(ushort4*)(sxl + is) = make_ushort4(l4[0], l4[1], l4[2], l4[3]);
    }
    __syncthreads();
    const int wv = tid >> 6, lane = tid & 63;
    // Rebalanced: B-load groups per wave = {24,24,16,16,21,21,19,19}
    switch (wv) {
      case 0: gemm_task<0,0,0,1>(sxh,sxl,Bhi,Blo,Ibuf,row,f0,lane); break;
      case 1: gemm_task<0,0,1,1>(sxh,sxl,Bhi,Blo,Ibuf,row,f0,lane); break;
      case 2: gemm_task<1,0,0,2>(sxh,sxl,Bhi,Blo,Ibuf,row,f0,lane); break;
      case 3: gemm_task<1,1,0,2>(sxh,sxl,Bhi,Blo,Ibuf,row,f0,lane); break;
      case 4: gemm_task<2,0,0,2>(sxh,sxl,Bhi,Blo,Ibuf,row,f0,lane);
              gemm_task<5,0,0,2>(sxh,sxl,Bhi,Blo,Ibuf,row,f0,lane); break;
      case 5: gemm_task<2,1,0,2>(sxh,sxl,Bhi,Blo,Ibuf,row,f0,lane);
              gemm_task<5,1,0,2>(sxh,sxl,Bhi,Blo,Ibuf,row,f0,lane); break;
      case 6: gemm_task<3,0,0,2>(sxh,sxl,Bhi,Blo,Ibuf,row,f0,lane);
              gemm_task<4,0,0,2>(sxh,sxl,Bhi,Blo,Ibuf,row,f0,lane); break;
      default: gemm_task<3,1,0,2>(sxh,sxl,Bhi,Blo,Ibuf,row,f0,lane);
               gemm_task<5,2,0,2>(sxh,sxl,Bhi,Blo,Ibuf,row,f0,lane); break;
    }
  } else {
    const int row = b - 640;
    float* yl = (float*)sxh;   // 12 KB alias
    for (int i = tid; i < 3072; i += 512) yl[i] = ye[(size_t)row * 3072 + i];
    __syncthreads();
    const int wv = tid >> 6, lane = tid & 63;
    const int w = eW[wv], f = eF[wv];
    const int N = cW_N[w];
    const int nb = cW_CB[w + 1] - cW_CB[w];
    for (int jl = 0; jl < nb; ++jl) {
      const float2* cf = coeff + cW_CO[w] + (size_t)jl * N;
      float re = 0.0f, im = 0.0f;
      for (int n = lane; n < N; n += 64) {
        int pos = f * HOPSZ - (N >> 1) + n;
        if ((unsigned)pos < (unsigned)T_LEN) {
          int yi = (pos < 1536) ? pos : (pos - 318464 + 1536);
          float yv = yl[yi];
          float2 cs = cf[n];
          re = fmaf(yv, cs.x, re);
          im = fmaf(yv, cs.y, im);
        }
      }
#pragma unroll
      for (int off = 32; off > 0; off >>= 1) {
        re += __shfl_xor(re, off);
        im += __shfl_xor(im, off);
      }
      if (lane == 0)
        Ibuf[((size_t)row * NFRAMES + f) * NCOMP + (cW_CB[w] + jl)] = re * re + im * im;
    }
  }
}

// ================= E = I@W -> dB -> LUT -> n_inst, 16 frames per block =================
__global__ __launch_bounds__(256) void espec(const float* __restrict__ Ibuf,
                                             const float* __restrict__ Wmat,
                                             const float* __restrict__ lut,
                                             float* __restrict__ ninst) {
  __shared__ float Is[16][68];
  __shared__ float luts[88];
  const int row = blockIdx.y;
  const int fb = blockIdx.x * 16;
  const int tid = threadIdx.x;
  if (tid < 88) luts[tid] = lut[tid];
  for (int u = tid; u < 16 * NCOMP; u += 256) {
    int fi = u / NCOMP, j = u - fi * NCOMP;
    int f = fb + fi;
    Is[fi][j] = (f < NFRAMES) ? Ibuf[((size_t)row * NFRAMES + f) * NCOMP + j] : 0.0f;
  }
  __syncthreads();
  for (int u = tid; u < 16 * NCH; u += 256) {
    int fi = u / NCH, c = u - fi * NCH;
    int f = fb + fi;
    if (f >= NFRAMES) continue;
    float e = 0.0f;
#pragma unroll 4
    for (int j = 0; j < NCOMP; ++j) e = fmaf(Is[fi][j], Wmat[j * NCH + c], e);
    float edb = 10.0f * log10f(e * 2.5e9f + 1e-12f);   // 1/I0 = 2.5e9
    float xv = fminf(fmaxf(edb, 0.0f), 110.0f);
    float u2 = xv * (87.0f / 110.0f);
    int i0 = (int)u2; if (i0 > 86) i0 = 86;
    float fr = u2 - (float)i0;
    float nv = fmaf(luts[i0 + 1] - luts[i0], fr, luts[i0]);
    ninst[((size_t)row * NFRAMES + f) * NCH + c] = nv;
  }
}

// ================= short-term AGC (16-deep pipelined, branch-free main loop) =================
__global__ __launch_bounds__(64) void agc1(const float* __restrict__ ninst,
                                           float* __restrict__ stl) {
  int idx = blockIdx.x * 64 + threadIdx.x;
  if (idx >= NROWS * NCH) return;
  int row = idx / NCH, c = idx - row * NCH;
  const float* src = ninst + (size_t)row * NFRAMES * NCH + c;
  float* dst = stl + (size_t)row * NFRAMES * NCH + c;
  float buf[16], cur[16];
#pragma unroll
  for (int i = 0; i < 16; ++i) buf[i] = src[(size_t)i * NCH];
  float s = 0.0f;
  // main: f = 0..607 ; prefetch f+16 (max 623) unconditional
  for (int fb = 0; fb < 608; fb += 16) {
#pragma unroll
    for (int i = 0; i < 16; ++i) cur[i] = buf[i];
#pragma unroll
    for (int i = 0; i < 16; ++i) buf[i] = src[(size_t)(fb + 16 + i) * NCH];
#pragma unroll
    for (int j = 0; j < 16; ++j) {
      float xv = cur[j];
      float a = (xv > s) ? 0.045f : 0.033f;
      s = a * xv + (1.0f - a) * s;
      dst[(size_t)(fb + j) * NCH] = s;
    }
  }
  // tail: f = 608..623 from buf, then 624 direct
#pragma unroll
  for (int j = 0; j < 16; ++j) {
    float xv = buf[j];
    float a = (xv > s) ? 0.045f : 0.033f;
    s = a * xv + (1.0f - a) * s;
    dst[(size_t)(608 + j) * NCH] = s;
  }
  float xv = src[(size_t)624 * NCH];
  float a = (xv > s) ? 0.045f : 0.033f;
  s = a * xv + (1.0f - a) * s;
  dst[(size_t)624 * NCH] = s;
}

// ================= ERB smoothing + binaural inhibition + channel sum, 8 frames/block =================
__global__ __launch_bounds__(256) void combine(const float* __restrict__ stl,
                                               const float* __restrict__ gauss,
                                               float* __restrict__ outL,
                                               float* __restrict__ outR) {
  __shared__ float sl[8][168], sr[8][168], gsh[17];
  const int b = blockIdx.y, fb = blockIdx.x * 8;
  const int tid = threadIdx.x;
  if (tid < 17) gsh[tid] = gauss[tid];
  for (int u = tid; u < 8 * 168; u += 256) {
    int fi = u / 168, c = u - fi * 168;
    sl[fi][c] = 0.0f; sr[fi][c] = 0.0f;
  }
  __syncthreads();
  for (int u = tid; u < 8 * 300; u += 256) {
    int fi = u / 300, r = u - fi * 300;
    int f = fb + fi;
    if (f < NFRAMES) {
      int ch = (r < NCH) ? 0 : 1;
      int c = (r < NCH) ? r : r - NCH;
      float v = stl[((size_t)(b * 2 + ch) * NFRAMES + f) * NCH + c];
      if (ch == 0) sl[fi][8 + c] = v; else sr[fi][8 + c] = v;
    }
  }
  __syncthreads();
  const int wv = tid >> 6, lane = tid & 63;
#pragma unroll
  for (int fi2 = 0; fi2 < 2; ++fi2) {
    const int fi = wv * 2 + fi2;
    const int f = fb + fi;
    float pvl = 0.0f, pvr = 0.0f;
#pragma unroll
    for (int s = 0; s < 3; ++s) {
      int c = lane + 64 * s;
      if (c < NCH) {
        float smL = 0.0f, smR = 0.0f;
#pragma unroll
        for (int t = 0; t < 17; ++t) {
          smL = fmaf(gsh[t], sl[fi][c + t], smL);
          smR = fmaf(gsh[t], sr[fi][c + t], smR);
        }
        // sech(z) = 2t/(1+t^2), t = e^-z  (z >= 0 here)
        float tR = __expf(-1.5978f * smR);
        float tL = __expf(-1.5978f * smL);
        pvl += smL * (2.0f * tR / fmaf(tR, tR, 1.0f));
        pvr += smR * (2.0f * tL / fmaf(tL, tL, 1.0f));
      }
    }
#pragma unroll
    for (int off = 32; off > 0; off >>= 1) {
      pvl += __shfl_xor(pvl, off);
      pvr += __shfl_xor(pvr, off);
    }
    if (lane == 0 && f < NFRAMES) {
      outL[b * NFRAMES + f] = pvl * 0.25f;
      outR[b * NFRAMES + f] = pvr * 0.25f;
    }
  }
}

// ================= long-term AGC + outputs: LDS-staged, 3-phase =================
__global__ __launch_bounds__(256) void final_k(const float* __restrict__ sLst,
                                               const float* __restrict__ sRst,
                                               float* __restrict__ out) {
  __shared__ float Ls[NB][641];   // padded stride: bank-conflict-free lane-per-batch reads
  __shared__ float Rs[NB][641];
  __shared__ float Lv[NB][641];
  const int tid = threadIdx.x;
  // phase 1: coalesced load + sOut
  for (int u = tid; u < NB * NFRAMES; u += 256) {
    int b = u / NFRAMES, f = u - b * NFRAMES;
    float a = sLst[u];
    float c = sRst[u];
    Ls[b][f] = a;
    Rs[b][f] = c;
    out[u] = a + c;                      // sLoud
  }
  __syncthreads();
  // phase 2: 16 lanes run the serial recurrence from LDS
  if (tid < NB) {
    const int b = tid;
    float ll = 0.0f, lr = 0.0f, mx = -3.4e38f;
    for (int f = 0; f < NFRAMES; ++f) {
      float a = Ls[b][f];
      float c = Rs[b][f];
      float aa = (a > ll) ? 0.01f : 0.00133f;
      ll = aa * a + (1.0f - aa) * ll;
      float ab = (c > lr) ? 0.01f : 0.00133f;
      lr = ab * c + (1.0f - ab) * lr;
      float lv = ll + lr;
      Lv[b][f] = lv;
      mx = fmaxf(mx, lv);
    }
    out[2 * NB * NFRAMES + b] = mx;      // mLoud
  }
  __syncthreads();
  // phase 3: coalesced lOut
  for (int u = tid; u < NB * NFRAMES; u += 256) {
    int b = u / NFRAMES, f = u - b * NFRAMES;
    out[NB * NFRAMES + u] = Lv[b][f];    // lLoud
  }
}

extern "C" void kernel_launch(void* const* d_in, const int* in_sizes, int n_in,
                              void* d_out, int out_size, void* d_ws, size_t ws_size,
                              hipStream_t stream) {
  const float* audio = (const float*)d_in[0];
  const float* ear   = (const float*)d_in[1];
  const float* lut   = (const float*)d_in[2];
  char* ws = (char*)d_ws;

  unsigned short* BhiT   = (unsigned short*)(ws);            //   983,040 B
  unsigned short* BloT   = (unsigned short*)(ws + 983040);   //   983,040 B
  float2*         coeffO = (float2*)(ws + 1966080);          //   260,608 B
  float*          Wmat   = (float*)(ws + 2226688);           //    40,200 B
  float*          gauss  = (float*)(ws + 2266888);           //        68 B
  float*          yedge  = (float*)(ws + 2266960);           //   393,216 B
  float*          Ibuf   = (float*)(ws + 2660176);           // 5,360,000 B
  float*          ninst  = (float*)(ws + 8020176);           // 12,000,000 B
  float*          stl    = (float*)(ws + 20020176);          // 12,000,000 B
  float*          stlL   = (float*)(ws + 32020176);          //    40,000 B
  float*          stlR   = (float*)(ws + 32060176);          //    40,000 B

  hipLaunchKernelGGL(setup_k, dim3(965), dim3(256), 0, stream,
                     ear, audio, coeffO, Wmat, gauss, BhiT, BloT, yedge);
  hipLaunchKernelGGL(sparse2, dim3(672), dim3(512), 0, stream,
                     audio, BhiT, BloT, coeffO, yedge, Ibuf);
  hipLaunchKernelGGL(espec, dim3(40, 32), dim3(256), 0, stream, Ibuf, Wmat, lut, ninst);
  hipLaunchKernelGGL(agc1, dim3(75), dim3(64), 0, stream, ninst, stl);
  hipLaunchKernelGGL(combine, dim3(79, 16), dim3(256), 0, stream, stl, gauss, stlL, stlR);
  hipLaunchKernelGGL(final_k, dim3(1), dim3(256), 0, stream, stlL, stlR, (float*)d_out);
}